// Round 13
// baseline (125.364 us; speedup 1.0000x reference)
//
#include <hip/hip_runtime.h>
#include <math.h>

#define CB 16
#define CL 2048
#define CD 512
#define CE 8
#define CH 8
#define CEH 64
#define CF 2048

typedef __bf16 bf16x8 __attribute__((ext_vector_type(8)));
typedef float f32x4 __attribute__((ext_vector_type(4)));

#define GLL16(srcp, dstp) __builtin_amdgcn_global_load_lds( \
    (const __attribute__((address_space(1))) unsigned int*)(srcp), \
    (__attribute__((address_space(3))) unsigned int*)(dstp), 16, 0, 0)

// ws layout (float offsets)
#define WS_GATES 0
#define WS_XN    (WS_GATES + CB*CE)
#define WS_QN    (WS_XN + CB*CD)
#define WS_QH    (WS_QN + CB*CE*CD)
#define WS_SBIAS (WS_QH + CB*CE*CD)
#define WS_WK    (WS_SBIAS + CB*CE*CH)          /* bf16 wkh [b][eh][d] */
#define WS_SC    (WS_WK + CB*CEH*CD)            /* fp32 sc [b][eh][l]; partials alias (liveness disjoint) */
#define WS_PART  WS_SC
#define WS_PART1 (WS_PART + 524288)
#define WS_ENT   (WS_SC + CB*CL*CEH)            /* [b][e][8] chunk partials */
#define WS_ATTN  (WS_ENT + CB*CE*8)
#define WS_X     (WS_ATTN + CB*CE*CD)
#define WS_XO    (WS_X + CB*CE*CD)
#define WS_HB    (WS_XO + CB*CE*CD)
#define WS_RP    (WS_HB + CB*CE*CF)             /* 8 * CB*CEH*CD fp32 partials; lmax/lsum alias head; W2 partials reuse */
#define WS_PB16  (WS_RP + 8*CB*CEH*CD)          /* bf16 probs [b][eh][l] */

// k1: gating softmax + LN of query + per-expert affine (writes qn directly).
__global__ __launch_bounds__(256) void k1_gates_qn(
    const float* __restrict__ q, const float* __restrict__ wg,
    const float* __restrict__ g, const float* __restrict__ bln,
    float* __restrict__ qn, float* __restrict__ gates) {
  int b = blockIdx.x, t = threadIdx.x;
  int w = t >> 6, lane = t & 63;
  __shared__ float r1[4], r2[4];
  __shared__ float gp[4][8];
  float v0 = q[b*CD + t], v1 = q[b*CD + 256 + t];
  float s = v0 + v1;
  #pragma unroll
  for (int m = 32; m >= 1; m >>= 1) s += __shfl_xor(s, m);
  if (lane == 0) r1[w] = s;
  __syncthreads();
  float mu = (r1[0]+r1[1]+r1[2]+r1[3]) * (1.0f/CD);
  float c0 = v0 - mu, c1 = v1 - mu;
  s = c0*c0 + c1*c1;
  #pragma unroll
  for (int m = 32; m >= 1; m >>= 1) s += __shfl_xor(s, m);
  if (lane == 0) r2[w] = s;
  float ge[CE];
  #pragma unroll
  for (int e = 0; e < CE; e++) ge[e] = v0 * wg[t*CE + e] + v1 * wg[(256+t)*CE + e];
  #pragma unroll
  for (int m = 32; m >= 1; m >>= 1) {
    #pragma unroll
    for (int e = 0; e < CE; e++) ge[e] += __shfl_xor(ge[e], m);
  }
  if (lane == 0) {
    #pragma unroll
    for (int e = 0; e < CE; e++) gp[w][e] = ge[e];
  }
  __syncthreads();
  float rstd = rsqrtf((r2[0]+r2[1]+r2[2]+r2[3]) * (1.0f/CD) + 1e-5f);
  float xn0 = c0 * rstd, xn1 = c1 * rstd;
  #pragma unroll
  for (int e = 0; e < CE; e++) {
    qn[(b*CE + e)*CD + t]       = xn0 * g[e*CD + t]       + bln[e*CD + t];
    qn[(b*CE + e)*CD + 256 + t] = xn1 * g[e*CD + 256 + t] + bln[e*CD + 256 + t];
  }
  if (t == 0) {
    float logit[CE];
    float m = -1e30f;
    #pragma unroll
    for (int e = 0; e < CE; e++) {
      logit[e] = gp[0][e] + gp[1][e] + gp[2][e] + gp[3][e];
      m = fmaxf(m, logit[e]);
    }
    float ssum = 0.f, ex[CE];
    #pragma unroll
    for (int e = 0; e < CE; e++) { ex[e] = __expf(logit[e] - m); ssum += ex[e]; }
    #pragma unroll
    for (int e = 0; e < CE; e++) gates[b*CE + e] = ex[e] / ssum;
  }
}

// Streaming split-K GEMV16: out_partial[kc][b][e][n] = sum_k X[b,e,k]*W[e,k,n]
template<int KC>
__global__ __launch_bounds__(256) void gstream(
    const float* __restrict__ X, int xb_, int xe_,
    const float* __restrict__ W, size_t we_, int ldw,
    float* __restrict__ P, int ntiles, size_t pc_, int pb_, int pe_) {
  int e = blockIdx.y;
  int nt = blockIdx.x % ntiles, kc = blockIdx.x / ntiles;
  int n0 = nt * 64, k0 = kc * KC;
  __shared__ float xs[KC][16];
  __shared__ float red[16][64];
  int t = threadIdx.x;
  for (int idx = t; idx < KC * 16; idx += 256) {
    int k = idx >> 4, b = idx & 15;
    xs[k][b] = X[(size_t)b * xb_ + (size_t)e * xe_ + k0 + k];
  }
  __syncthreads();
  int n = t & 63, kq = t >> 6;
  float acc[16] = {};
  const float* Wp = W + (size_t)e * we_ + (size_t)k0 * ldw + n0 + n;
  #pragma unroll 4
  for (int k = kq * (KC/4); k < (kq+1) * (KC/4); k++) {
    float w = Wp[(size_t)k * ldw];
    const float4* xp = reinterpret_cast<const float4*>(xs[k]);
    float4 x0 = xp[0], x1 = xp[1], x2 = xp[2], x3 = xp[3];
    acc[0]  += x0.x*w; acc[1]  += x0.y*w; acc[2]  += x0.z*w; acc[3]  += x0.w*w;
    acc[4]  += x1.x*w; acc[5]  += x1.y*w; acc[6]  += x1.z*w; acc[7]  += x1.w*w;
    acc[8]  += x2.x*w; acc[9]  += x2.y*w; acc[10] += x2.z*w; acc[11] += x2.w*w;
    acc[12] += x3.x*w; acc[13] += x3.y*w; acc[14] += x3.z*w; acc[15] += x3.w*w;
  }
  if (kq == 0) {
    #pragma unroll
    for (int b = 0; b < 16; b++) red[b][n] = acc[b];
  }
  __syncthreads();
  #pragma unroll
  for (int qq = 1; qq < 4; qq++) {
    if (kq == qq) {
      #pragma unroll
      for (int b = 0; b < 16; b++) red[b][n] += acc[b];
    }
    __syncthreads();
  }
  #pragma unroll
  for (int i = 0; i < 4; i++) {
    int b = kq*4 + i;
    P[(size_t)kc*pc_ + (size_t)b*pb_ + (size_t)e*pe_ + n0 + n] = red[b][n];
  }
}

// Wv variant: sums the 8 k6 partials during staging, then streams Wv column block.
__global__ __launch_bounds__(256) void gstream_v(
    const float* __restrict__ rp, const float* __restrict__ Wv,
    float* __restrict__ P) {
  int eh = blockIdx.y, kc = blockIdx.x;
  int e = eh >> 3, h = eh & 7;
  int k0 = kc * 64;
  __shared__ float xs[64][20];
  __shared__ float red[16][64];
  int t = threadIdx.x;
  for (int idx = t; idx < 64 * 16; idx += 256) {
    int k = idx & 63, b = idx >> 6;   // k fastest -> coalesced
    float s = 0.f;
    #pragma unroll
    for (int c = 0; c < 8; c++)
      s += rp[(size_t)c*(CB*CEH*CD) + ((size_t)(b*CEH + eh))*CD + k0 + k];
    xs[k][b] = s;
  }
  __syncthreads();
  int n = t & 63, kq = t >> 6;
  float acc[16] = {};
  const float* Wp = Wv + (size_t)e*CD*CD + (size_t)k0*CD + h*64 + n;
  #pragma unroll 4
  for (int k = kq*16; k < kq*16 + 16; k++) {
    float w = Wp[(size_t)k * CD];
    const float4* xp = reinterpret_cast<const float4*>(&xs[k][0]);
    float4 x0 = xp[0], x1 = xp[1], x2 = xp[2], x3 = xp[3];
    acc[0]  += x0.x*w; acc[1]  += x0.y*w; acc[2]  += x0.z*w; acc[3]  += x0.w*w;
    acc[4]  += x1.x*w; acc[5]  += x1.y*w; acc[6]  += x1.z*w; acc[7]  += x1.w*w;
    acc[8]  += x2.x*w; acc[9]  += x2.y*w; acc[10] += x2.z*w; acc[11] += x2.w*w;
    acc[12] += x3.x*w; acc[13] += x3.y*w; acc[14] += x3.z*w; acc[15] += x3.w*w;
  }
  if (kq == 0) { 
    #pragma unroll
    for (int b = 0; b < 16; b++) red[b][n] = acc[b]; }
  __syncthreads();
  #pragma unroll
  for (int qq = 1; qq < 4; qq++) {
    if (kq == qq) {
      #pragma unroll
      for (int b = 0; b < 16; b++) red[b][n] += acc[b];
    }
    __syncthreads();
  }
  #pragma unroll
  for (int i = 0; i < 4; i++) {
    int b = kq*4 + i;
    P[(size_t)kc*65536 + (size_t)b*4096 + (size_t)eh*64 + n] = red[b][n];
  }
}

// Wo stream: staging computes attn = sum(Pv partials) + bv, then streams Wo.
__global__ __launch_bounds__(256) void gstream_wo(
    const float* __restrict__ Pv, const float* __restrict__ bv,
    const float* __restrict__ Wo, float* __restrict__ P) {
  int e = blockIdx.y;
  int nt = blockIdx.x % 8, kc = blockIdx.x / 8;
  int n0 = nt * 64, k0 = kc * 64;
  __shared__ float xs[64][20];
  __shared__ float red[16][64];
  int t = threadIdx.x;
  for (int idx = t; idx < 64 * 16; idx += 256) {
    int k = idx & 63, b = idx >> 6;   // k fastest -> coalesced
    float s = bv[e*CD + k0 + k];
    #pragma unroll
    for (int c = 0; c < 8; c++)
      s += Pv[(size_t)c*65536 + (size_t)b*4096 + e*512 + k0 + k];
    xs[k][b] = s;
  }
  __syncthreads();
  int n = t & 63, kq = t >> 6;
  float acc[16] = {};
  const float* Wp = Wo + (size_t)e*CD*CD + (size_t)k0*CD + n0 + n;
  #pragma unroll 4
  for (int k = kq*16; k < kq*16 + 16; k++) {
    float w = Wp[(size_t)k * CD];
    const float4* xp = reinterpret_cast<const float4*>(&xs[k][0]);
    float4 x0 = xp[0], x1 = xp[1], x2 = xp[2], x3 = xp[3];
    acc[0]  += x0.x*w; acc[1]  += x0.y*w; acc[2]  += x0.z*w; acc[3]  += x0.w*w;
    acc[4]  += x1.x*w; acc[5]  += x1.y*w; acc[6]  += x1.z*w; acc[7]  += x1.w*w;
    acc[8]  += x2.x*w; acc[9]  += x2.y*w; acc[10] += x2.z*w; acc[11] += x2.w*w;
    acc[12] += x3.x*w; acc[13] += x3.y*w; acc[14] += x3.z*w; acc[15] += x3.w*w;
  }
  if (kq == 0) {
    #pragma unroll
    for (int b = 0; b < 16; b++) red[b][n] = acc[b]; }
  __syncthreads();
  #pragma unroll
  for (int qq = 1; qq < 4; qq++) {
    if (kq == qq) {
      #pragma unroll
      for (int b = 0; b < 16; b++) red[b][n] += acc[b];
    }
    __syncthreads();
  }
  #pragma unroll
  for (int i = 0; i < 4; i++) {
    int b = kq*4 + i;
    P[(size_t)kc*65536 + (size_t)b*4096 + (size_t)e*512 + n0 + n] = red[b][n];
  }
}

// W2 stream: staging computes h = gelu(sum(4 FFN1 partials) + b1), streams W2.
__global__ __launch_bounds__(256) void gstream_w2(
    const float* __restrict__ P1, const float* __restrict__ b1,
    const float* __restrict__ W2, float* __restrict__ Pout) {
  int e = blockIdx.y;
  int nt = blockIdx.x % 8, kc = blockIdx.x / 8;
  int n0 = nt * 64, k0 = kc * 256;
  __shared__ float xs[256][20];
  __shared__ float red[16][64];
  int t = threadIdx.x;
  for (int idx = t; idx < 256 * 16; idx += 256) {
    int k = idx & 255, b = idx >> 8;   // k fastest -> coalesced
    float v = b1[e*CF + k0 + k];
    #pragma unroll
    for (int c = 0; c < 4; c++)
      v += P1[(size_t)c*262144 + (size_t)b*16384 + e*2048 + k0 + k];
    xs[k][b] = 0.5f*v*(1.f + erff(v*0.70710678118f));
  }
  __syncthreads();
  int n = t & 63, kq = t >> 6;
  float acc[16] = {};
  const float* Wp = W2 + (size_t)e*CF*CD + (size_t)k0*CD + n0 + n;
  #pragma unroll 4
  for (int k = kq*64; k < kq*64 + 64; k++) {
    float w = Wp[(size_t)k * CD];
    const float4* xp = reinterpret_cast<const float4*>(&xs[k][0]);
    float4 x0 = xp[0], x1 = xp[1], x2 = xp[2], x3 = xp[3];
    acc[0]  += x0.x*w; acc[1]  += x0.y*w; acc[2]  += x0.z*w; acc[3]  += x0.w*w;
    acc[4]  += x1.x*w; acc[5]  += x1.y*w; acc[6]  += x1.z*w; acc[7]  += x1.w*w;
    acc[8]  += x2.x*w; acc[9]  += x2.y*w; acc[10] += x2.z*w; acc[11] += x2.w*w;
    acc[12] += x3.x*w; acc[13] += x3.y*w; acc[14] += x3.z*w; acc[15] += x3.w*w;
  }
  if (kq == 0) {
    #pragma unroll
    for (int b = 0; b < 16; b++) red[b][n] = acc[b]; }
  __syncthreads();
  #pragma unroll
  for (int qq = 1; qq < 4; qq++) {
    if (kq == qq) {
      #pragma unroll
      for (int b = 0; b < 16; b++) red[b][n] += acc[b];
    }
    __syncthreads();
  }
  #pragma unroll
  for (int i = 0; i < 4; i++) {
    int b = kq*4 + i;
    Pout[(size_t)kc*65536 + (size_t)b*4096 + (size_t)e*512 + n0 + n] = red[b][n];
  }
}

// x = q + sum partials + bo; then LayerNorm -> xo (writes both)
__global__ __launch_bounds__(512) void comb_o_lno(
    const float* __restrict__ P, const float* __restrict__ bo,
    const float* __restrict__ q, const float* __restrict__ g,
    const float* __restrict__ bb, float* __restrict__ xb,
    float* __restrict__ xo) {
  int be = blockIdx.x, b = be >> 3, e = be & 7, t = threadIdx.x;
  float v = q[b*CD + t] + bo[e*CD + t];
  #pragma unroll
  for (int c = 0; c < 8; c++)
    v += P[(size_t)c*65536 + (size_t)b*4096 + e*512 + t];
  xb[be*CD + t] = v;
  __shared__ float red[512];
  red[t] = v; __syncthreads();
  for (int s = 256; s > 0; s >>= 1) { if (t < s) red[t] += red[t+s]; __syncthreads(); }
  float mu = red[0] * (1.0f/CD); __syncthreads();
  float c0 = v - mu;
  red[t] = c0*c0; __syncthreads();
  for (int s = 256; s > 0; s >>= 1) { if (t < s) red[t] += red[t+s]; __syncthreads(); }
  float rstd = rsqrtf(red[0] * (1.0f/CD) + 1e-5f);
  xo[be*CD + t] = c0*rstd*g[e*CD + t] + bb[e*CD + t];
}

// yout = sum partials + b2 + x; gated mixture -> fused, gtout
__global__ __launch_bounds__(512) void comb_ffn2_final(
    const float* __restrict__ P, const float* __restrict__ b2,
    const float* __restrict__ xb, const float* __restrict__ gates,
    const float* __restrict__ entp, float* __restrict__ yout,
    float* __restrict__ fused, float* __restrict__ gtout) {
  int b = blockIdx.x, t = threadIdx.x;
  __shared__ float gt_s[CE];
  if (t < CE) {
    float Hs = 0.f;
    #pragma unroll
    for (int c = 0; c < 8; c++) Hs += entp[(b*CE + t)*8 + c];
    gt_s[t] = gates[b*CE + t] * __expf(-0.5f * Hs);
  }
  __syncthreads();
  if (t == 0) {
    float s = 0.f;
    for (int e = 0; e < CE; e++) s += gt_s[e];
    s += 1e-9f;
    for (int e = 0; e < CE; e++) gt_s[e] /= s;
  }
  __syncthreads();
  float acc = 0.f;
  #pragma unroll
  for (int e = 0; e < CE; e++) {
    float y = b2[e*CD + t] + xb[(b*CE + e)*CD + t];
    #pragma unroll
    for (int c = 0; c < 8; c++)
      y += P[(size_t)c*65536 + (size_t)b*4096 + e*512 + t];
    yout[(b*CE + e)*CD + t] = y;
    acc += gt_s[e] * y;
  }
  fused[b*CD + t] = acc;  // ALPHA = 1.0 -> fused == mixture
  if (t < CE) gtout[b*CE + t] = gt_s[t];
}

// k4: wk_eff = Wk_slice^T @ qh (qh combined from Wq partials inline, coalesced) -> bf16 wkh;
// dt==0 block also emits sbias[b][e][h] = qh_hslice . bk_hslice.
__global__ __launch_bounds__(256) void k4_wkeff(
    const float* __restrict__ Wk, const float* __restrict__ Pq,
    const float* __restrict__ bq, const float* __restrict__ bk,
    __bf16* __restrict__ wkh, float* __restrict__ sbias) {
  int e = blockIdx.y;
  int h = blockIdx.x >> 3, dt = blockIdx.x & 7;
  int d0 = dt * 64;
  __shared__ float wks[64][65];   // [c][d]
  __shared__ float qs[64][20];    // [c][b] (pad 20: 16B-aligned rows)
  __shared__ float red[16][64];
  int t = threadIdx.x;
  for (int idx = t; idx < 64*64; idx += 256) {
    int c = idx & 63, d = idx >> 6;
    wks[c][d] = Wk[(size_t)e*CD*CD + (size_t)(d0+d)*CD + h*64 + c];
  }
  for (int idx = t; idx < 64*16; idx += 256) {
    int c = idx & 63, b = idx >> 6;   // c fastest -> coalesced partial reads
    float s = bq[e*CD + h*64 + c];
    #pragma unroll
    for (int cc = 0; cc < 8; cc++)
      s += Pq[(size_t)cc*65536 + (size_t)b*4096 + e*512 + h*64 + c];
    qs[c][b] = s;
  }
  __syncthreads();
  if (dt == 0) {
    int bb = t >> 4, ii = t & 15;
    float p = 0.f;
    #pragma unroll
    for (int j = 0; j < 4; j++)
      p += qs[ii*4 + j][bb] * bk[e*CD + h*64 + ii*4 + j];
    p += __shfl_xor(p, 1);
    p += __shfl_xor(p, 2);
    p += __shfl_xor(p, 4);
    p += __shfl_xor(p, 8);
    if (ii == 0) sbias[bb*CEH + e*8 + h] = p;
  }
  int d = t & 63, cq = t >> 6;
  float acc[16] = {};
  #pragma unroll 4
  for (int c = cq*16; c < cq*16 + 16; c++) {
    float w = wks[c][d];
    const float4* xp = reinterpret_cast<const float4*>(&qs[c][0]);
    float4 x0 = xp[0], x1 = xp[1], x2 = xp[2], x3 = xp[3];
    acc[0]  += x0.x*w; acc[1]  += x0.y*w; acc[2]  += x0.z*w; acc[3]  += x0.w*w;
    acc[4]  += x1.x*w; acc[5]  += x1.y*w; acc[6]  += x1.z*w; acc[7]  += x1.w*w;
    acc[8]  += x2.x*w; acc[9]  += x2.y*w; acc[10] += x2.z*w; acc[11] += x2.w*w;
    acc[12] += x3.x*w; acc[13] += x3.y*w; acc[14] += x3.z*w; acc[15] += x3.w*w;
  }
  if (cq == 0) { 
    #pragma unroll
    for (int b = 0; b < 16; b++) red[b][d] = acc[b]; }
  __syncthreads();
  #pragma unroll
  for (int qq = 1; qq < 4; qq++) {
    if (cq == qq) {
      #pragma unroll
      for (int b = 0; b < 16; b++) red[b][d] += acc[b];
    }
    __syncthreads();
  }
  int eh = e*8 + h;
  #pragma unroll
  for (int i = 0; i < 4; i++) {
    int b = cq*4 + i;
    wkh[((size_t)(b*CEH + eh))*CD + d0 + d] = (__bf16)red[b][d];
  }
}

// sc[b][eh][l] = (ret[b][l][:]·wk_eff[b][eh][:] + qh·bk)/8 via bf16 MFMA.
// 3-buffer global_load_lds pipeline, counted vmcnt(4) across raw s_barrier
// (each thread issues exactly 4 GLL16 per stage; vmcnt(4) = prior stage done).
__global__ __launch_bounds__(256) void k5_mfma(
    const float* __restrict__ ret, const __bf16* __restrict__ wkh,
    const float* __restrict__ sbias, float* __restrict__ sc,
    float* __restrict__ lmax, float* __restrict__ lsum) {
  int b = blockIdx.y, lt = blockIdx.x, t = threadIdx.x;
  int w = t >> 6, lane = t & 63;
  int lnlo = lane & 15, lnhi = lane >> 4;
  int lh = w & 1, ehh = w >> 1;
  int l0blk = lt*32;
  int ehbase = ehh*32;
  __shared__ __align__(16) char ldsbuf[49152];   // 3 x (ret 8KB) + 3 x (wkh 8KB)
  f32x4 acc[2];
  acc[0] = (f32x4){0.f,0.f,0.f,0.f};
  acc[1] = (f32x4){0.f,0.f,0.f,0.f};
  const float*  retb  = ret + (size_t)(b*CL + l0blk)*CD;
  const __bf16* wkhb  = wkh + (size_t)b*CEH*CD;

  int rs0 = t,        rl0 = rs0 >> 4, rg0 = ((rs0 & 15) ^ (rl0 & 15)) << 2;
  int rs1 = t + 256,  rl1 = rs1 >> 4, rg1 = ((rs1 & 15) ^ (rl1 & 15)) << 2;
  int ws0 = t,        we0 = ws0 >> 3, wg0 = ((ws0 & 7) ^ (we0 & 7)) << 3;
  int ws1 = t + 256,  we1 = ws1 >> 3, wg1 = ((ws1 & 7) ^ (we1 & 7)) << 3;

  #define K5_STAGE(bufi, kt) do {                                          \
    char* rB = ldsbuf + (bufi)*8192;                                       \
    char* wB = ldsbuf + 24576 + (bufi)*8192;                               \
    int dofs = (kt)*64;                                                    \
    GLL16(retb + (size_t)rl0*CD + dofs + rg0, rB + rs0*16);                \
    GLL16(retb + (size_t)rl1*CD + dofs + rg1, rB + rs1*16);                \
    GLL16(wkhb + (size_t)we0*CD + dofs + wg0, wB + ws0*16);                \
    GLL16(wkhb + (size_t)we1*CD + dofs + wg1, wB + ws1*16);                \
  } while (0)

  K5_STAGE(0, 0);
  K5_STAGE(1, 1);
  asm volatile("s_waitcnt vmcnt(4)" ::: "memory");
  __builtin_amdgcn_sched_barrier(0);
  __builtin_amdgcn_s_barrier();
  __builtin_amdgcn_sched_barrier(0);
  #pragma unroll
  for (int kt = 0; kt < 8; kt++) {
    int cur = kt % 3;
    if (kt < 6) K5_STAGE((kt + 2) % 3, kt + 2);
    const char* rB = ldsbuf + cur*8192;
    const char* wB = ldsbuf + 24576 + cur*8192;
    #pragma unroll
    for (int sub = 0; sub < 2; sub++) {
      int g0 = (sub*8 + lnhi*2 + 0) ^ lnlo;
      int g1 = (sub*8 + lnhi*2 + 1) ^ lnlo;
      float4 f0 = *reinterpret_cast<const float4*>(rB + (lh*16 + lnlo)*256 + g0*16);
      float4 f1 = *reinterpret_cast<const float4*>(rB + (lh*16 + lnlo)*256 + g1*16);
      bf16x8 bfrag;
      bfrag[0]=(__bf16)f0.x; bfrag[1]=(__bf16)f0.y; bfrag[2]=(__bf16)f0.z; bfrag[3]=(__bf16)f0.w;
      bfrag[4]=(__bf16)f1.x; bfrag[5]=(__bf16)f1.y; bfrag[6]=(__bf16)f1.z; bfrag[7]=(__bf16)f1.w;
      int ga = (sub*4 + lnhi) ^ (lnlo & 7);
      bf16x8 a0 = *reinterpret_cast<const bf16x8*>(wB + (ehbase + 0*16 + lnlo)*128 + ga*16);
      bf16x8 a1 = *reinterpret_cast<const bf16x8*>(wB + (ehbase + 1*16 + lnlo)*128 + ga*16);
      acc[0] = __builtin_amdgcn_mfma_f32_16x16x32_bf16(a0, bfrag, acc[0], 0, 0, 0);
      acc[1] = __builtin_amdgcn_mfma_f32_16x16x32_bf16(a1, bfrag, acc[1], 0, 0, 0);
    }
    if (kt < 7) {
      if (kt < 6) asm volatile("s_waitcnt vmcnt(4)" ::: "memory");
      else        asm volatile("s_waitcnt vmcnt(0)" ::: "memory");
      __builtin_amdgcn_sched_barrier(0);
      __builtin_amdgcn_s_barrier();
      __builtin_amdgcn_sched_barrier(0);
    }
  }
  #undef K5_STAGE

  int strip = lt*2 + lh;
  int l = l0blk + lh*16 + lnlo;
  #pragma unroll
  for (int et = 0; et < 2; et++) {
    #pragma unroll
    for (int i = 0; i < 4; i++) {
      int eh = ehbase + et*16 + lnhi*4 + i;
      float v = acc[et][i]*0.125f + sbias[b*CEH + eh]*0.125f;
      sc[((size_t)(b*CEH + eh))*CL + l] = v;
      float m = v;
      m = fmaxf(m, __shfl_xor(m, 1));
      m = fmaxf(m, __shfl_xor(m, 2));
      m = fmaxf(m, __shfl_xor(m, 4));
      m = fmaxf(m, __shfl_xor(m, 8));
      float s = __expf(v - m);
      s += __shfl_xor(s, 1);
      s += __shfl_xor(s, 2);
      s += __shfl_xor(s, 4);
      s += __shfl_xor(s, 8);
      if (lnlo == et*4 + i) {
        lmax[((size_t)(b*CEH + eh))*128 + strip] = m;
        lsum[((size_t)(b*CEH + eh))*128 + strip] = s;
      }
    }
  }
}

// normalize sc -> bf16 probs pb; row softmax stats reduced inline from lmax/lsum;
// entropy partials per (b,e,lchunk)
__global__ __launch_bounds__(256) void k5n(
    const float* __restrict__ sc, const float* __restrict__ lmax,
    const float* __restrict__ lsum, __bf16* __restrict__ pb,
    float* __restrict__ entp) {
  int e = blockIdx.x, b = blockIdx.y, lc = blockIdx.z, t = threadIdx.x;
  __shared__ float M_s[8], I_s[8];
  {
    int g = t >> 5, lane = t & 31;
    int eh = e*8 + g;
    const float* lm = lmax + ((size_t)(b*CEH + eh))*128;
    const float* ls = lsum + ((size_t)(b*CEH + eh))*128;
    float M = -1e30f, S = 0.f;
    #pragma unroll
    for (int j = 0; j < 4; j++) {
      float m2 = lm[lane + j*32], s2 = ls[lane + j*32];
      float Mn = fmaxf(M, m2);
      S = S*__expf(M - Mn) + s2*__expf(m2 - Mn);
      M = Mn;
    }
    #pragma unroll
    for (int mask = 16; mask >= 1; mask >>= 1) {
      float Mo = __shfl_xor(M, mask), So = __shfl_xor(S, mask);
      float Mn = fmaxf(M, Mo);
      S = S*__expf(M - Mn) + So*__expf(Mo - Mn);
      M = Mn;
    }
    if (lane == 0) { M_s[g] = M; I_s[g] = 1.f / S; }
  }
  __syncthreads();
  int l = lc*256 + t;
  float pbav = 0.f;
  #pragma unroll
  for (int h = 0; h < 8; h++) {
    size_t ix = ((size_t)(b*CEH + e*8 + h))*CL + l;
    float p = __expf(sc[ix] - M_s[h]) * I_s[h];
    pb[ix] = (__bf16)p;
    pbav += p;
  }
  pbav = fmaxf(pbav*0.125f, 1e-12f);
  float ent = -pbav * __logf(pbav);
  __shared__ float red[256];
  red[t] = ent; __syncthreads();
  for (int s = 128; s > 0; s >>= 1) { if (t < s) red[t] += red[t+s]; __syncthreads(); }
  if (t == 0) entp[(b*CE + e)*8 + lc] = red[0];
}

// reff partial[lc][b][eh][d] = sum_{l in chunk} P[b][eh][l] * ret[b][l][d] via bf16 MFMA.
__global__ __launch_bounds__(256) void k6_mfma(
    const __bf16* __restrict__ pb, const float* __restrict__ ret,
    float* __restrict__ part) {
  int b = blockIdx.y;
  int dt = blockIdx.x & 7, lc = blockIdx.x >> 3;
  int d0 = dt*64, l0 = lc*256;
  int t = threadIdx.x, w = t >> 6, lane = t & 63;
  int lnlo = lane & 15, lnhi = lane >> 4;
  __shared__ __bf16 Bs[2][64][40];   // [buf][d][l] transposed ret tile
  f32x4 acc[4];
  #pragma unroll
  for (int et = 0; et < 4; et++) acc[et] = (f32x4){0.f,0.f,0.f,0.f};
  const __bf16* pbb = pb + ((size_t)(b*CEH) + lnlo)*CL + l0 + lnhi*8;
  int srow = t & 31, scol = (t >> 5)*8;
  const float* retb = ret + ((size_t)(b*CL) + l0 + srow)*CD + d0 + scol;
  float4 v0 = *reinterpret_cast<const float4*>(retb);
  float4 v1 = *reinterpret_cast<const float4*>(retb + 4);
  bf16x8 ap0 = *reinterpret_cast<const bf16x8*>(pbb);
  bf16x8 ap1 = *reinterpret_cast<const bf16x8*>(pbb + (size_t)16*CL);
  bf16x8 ap2 = *reinterpret_cast<const bf16x8*>(pbb + (size_t)32*CL);
  bf16x8 ap3 = *reinterpret_cast<const bf16x8*>(pbb + (size_t)48*CL);
  #pragma unroll
  for (int kt = 0; kt < 8; kt++) {
    int cur = kt & 1;
    Bs[cur][scol+0][srow] = (__bf16)v0.x; Bs[cur][scol+1][srow] = (__bf16)v0.y;
    Bs[cur][scol+2][srow] = (__bf16)v0.z; Bs[cur][scol+3][srow] = (__bf16)v0.w;
    Bs[cur][scol+4][srow] = (__bf16)v1.x; Bs[cur][scol+5][srow] = (__bf16)v1.y;
    Bs[cur][scol+6][srow] = (__bf16)v1.z; Bs[cur][scol+7][srow] = (__bf16)v1.w;
    bf16x8 an0, an1, an2, an3;
    if (kt < 7) {
      v0 = *reinterpret_cast<const float4*>(retb + (size_t)(kt+1)*32*CD);
      v1 = *reinterpret_cast<const float4*>(retb + (size_t)(kt+1)*32*CD + 4);
      an0 = *reinterpret_cast<const bf16x8*>(pbb + (kt+1)*32);
      an1 = *reinterpret_cast<const bf16x8*>(pbb + (size_t)16*CL + (kt+1)*32);
      an2 = *reinterpret_cast<const bf16x8*>(pbb + (size_t)32*CL + (kt+1)*32);
      an3 = *reinterpret_cast<const bf16x8*>(pbb + (size_t)48*CL + (kt+1)*32);
    }
    __syncthreads();
    bf16x8 bfrag = *reinterpret_cast<const bf16x8*>(&Bs[cur][w*16 + lnlo][lnhi*8]);
    acc[0] = __builtin_amdgcn_mfma_f32_16x16x32_bf16(ap0, bfrag, acc[0], 0, 0, 0);
    acc[1] = __builtin_amdgcn_mfma_f32_16x16x32_bf16(ap1, bfrag, acc[1], 0, 0, 0);
    acc[2] = __builtin_amdgcn_mfma_f32_16x16x32_bf16(ap2, bfrag, acc[2], 0, 0, 0);
    acc[3] = __builtin_amdgcn_mfma_f32_16x16x32_bf16(ap3, bfrag, acc[3], 0, 0, 0);
    if (kt < 7) { ap0 = an0; ap1 = an1; ap2 = an2; ap3 = an3; }
  }
  float* dst = part + (size_t)lc*(CB*CEH*CD);
  int d = d0 + w*16 + lnlo;
  #pragma unroll
  for (int et = 0; et < 4; et++) {
    #pragma unroll
    for (int i = 0; i < 4; i++) {
      int eh = et*16 + lnhi*4 + i;
      dst[((size_t)(b*CEH + eh))*CD + d] = acc[et][i];
    }
  }
}

extern "C" void kernel_launch(void* const* d_in, const int* in_sizes, int n_in,
                              void* d_out, int out_size, void* d_ws, size_t ws_size,
                              hipStream_t stream) {
  const float* q    = (const float*)d_in[0];
  const float* ret  = (const float*)d_in[1];
  const float* wg   = (const float*)d_in[2];
  const float* lnqg = (const float*)d_in[3];
  const float* lnqb = (const float*)d_in[4];
  const float* Wq   = (const float*)d_in[5];
  const float* bq   = (const float*)d_in[6];
  const float* Wk   = (const float*)d_in[7];
  const float* bk   = (const float*)d_in[8];
  const float* Wv   = (const float*)d_in[9];
  const float* bv   = (const float*)d_in[10];
  const float* Wo   = (const float*)d_in[11];
  const float* bo   = (const float*)d_in[12];
  const float* lnog = (const float*)d_in[13];
  const float* lnob = (const float*)d_in[14];
  const float* W1   = (const float*)d_in[15];
  const float* b1   = (const float*)d_in[16];
  const float* W2   = (const float*)d_in[17];
  const float* b2   = (const float*)d_in[18];

  float* ws = (float*)d_ws;
  float* fused = (float*)d_out;
  float* yout  = fused + CB*CD;
  float* gtout = yout + CB*CE*CD;

  float* gates = ws + WS_GATES;
  float* qn    = ws + WS_QN;
  float* sbias = ws + WS_SBIAS;
  __bf16* wkh  = (__bf16*)(ws + WS_WK);
  float* sc    = ws + WS_SC;
  float* part0 = ws + WS_PART;
  float* part1 = ws + WS_PART1;
  float* entp  = ws + WS_ENT;
  float* xb    = ws + WS_X;
  float* xo    = ws + WS_XO;
  float* rpart = ws + WS_RP;
  __bf16* pb16 = (__bf16*)(ws + WS_PB16);
  float* lmax  = rpart;                      // dead before k6_mfma writes rpart
  float* lsum  = rpart + CB*CEH*128;

  k1_gates_qn<<<CB, 256, 0, stream>>>(q, wg, lnqg, lnqb, qn, gates);
  // qh partials = qn @ Wq : K=512 (8 chunks of 64), N=512 (8 tiles)
  gstream<64><<<dim3(64, CE), 256, 0, stream>>>(qn, CE*CD, CD, Wq, (size_t)CD*CD, CD,
                                                part0, 8, 65536, CE*CD, CD);
  // wk_eff (bf16) from Wk and combined qh; dt==0 blocks emit sbias
  k4_wkeff<<<dim3(64, CE), 256, 0, stream>>>(Wk, part0, bq, bk, wkh, sbias);
  k5_mfma<<<dim3(64, CB), 256, 0, stream>>>(ret, wkh, sbias, sc, lmax, lsum);
  k5n<<<dim3(CE, CB, 8), 256, 0, stream>>>(sc, lmax, lsum, pb16, entp);
  k6_mfma<<<dim3(64, CB), 256, 0, stream>>>(pb16, ret, rpart);
  // attn partials (over d-chunks) from reff(=sum rpart) @ Wv
  gstream_v<<<dim3(8, CEH), 256, 0, stream>>>(rpart, Wv, part1);
  // x-partials: (attn = sum part1 + bv) @ Wo
  gstream_wo<<<dim3(64, CE), 256, 0, stream>>>(part1, bv, Wo, part0);
  comb_o_lno<<<CB*CE, 512, 0, stream>>>(part0, bo, q, lnog, lnob, xb, xo);
  // FFN1 partials = xo @ W1 : K=512 (4 chunks of 128), N=2048 (32 tiles)
  gstream<128><<<dim3(128, CE), 256, 0, stream>>>(xo, CE*CD, CD, W1, (size_t)CD*CF, CF,
                                                  part0, 32, 262144, CE*CF, CF);
  // y-partials = gelu(FFN1) @ W2 : staging applies bias+GELU (coalesced); -> rpart
  gstream_w2<<<dim3(64, CE), 256, 0, stream>>>(part0, b1, W2, rpart);
  comb_ffn2_final<<<CB, 512, 0, stream>>>(rpart, b2, xb, gates, entp, yout, fused, gtout);
}

// Round 14
// 120.172 us; speedup vs baseline: 1.0432x; 1.0432x over previous
//
#include <hip/hip_runtime.h>
#include <math.h>

#define CB 16
#define CL 2048
#define CD 512
#define CE 8
#define CH 8
#define CEH 64
#define CF 2048

typedef __bf16 bf16x8 __attribute__((ext_vector_type(8)));
typedef float f32x4 __attribute__((ext_vector_type(4)));

#define GLL16(srcp, dstp) __builtin_amdgcn_global_load_lds( \
    (const __attribute__((address_space(1))) unsigned int*)(srcp), \
    (__attribute__((address_space(3))) unsigned int*)(dstp), 16, 0, 0)

// ws layout (float offsets)
#define WS_GATES 0
#define WS_XN    (WS_GATES + CB*CE)
#define WS_QN    (WS_XN + CB*CD)
#define WS_QH    (WS_QN + CB*CE*CD)
#define WS_SBIAS (WS_QH + CB*CE*CD)
#define WS_WK    (WS_SBIAS + CB*CE*CH)          /* bf16 wkh [b][eh][d] */
#define WS_SC    (WS_WK + CB*CEH*CD)            /* fp32 sc [b][eh][l]; partials alias (liveness disjoint) */
#define WS_PART  WS_SC
#define WS_PART1 (WS_PART + 524288)
#define WS_ENT   (WS_SC + CB*CL*CEH)            /* [b][e][8] chunk partials */
#define WS_ATTN  (WS_ENT + CB*CE*8)
#define WS_X     (WS_ATTN + CB*CE*CD)
#define WS_XO    (WS_X + CB*CE*CD)
#define WS_HB    (WS_XO + CB*CE*CD)
#define WS_RP    (WS_HB + CB*CE*CF)             /* 4 * CB*CEH*CD fp32 partials; lmax/lsum alias head; W2 partials reuse */
#define WS_PB16  (WS_RP + 8*CB*CEH*CD)          /* bf16 probs [b][eh][l] */

// k1: gating softmax + LN of query + per-expert affine (writes qn directly).
__global__ __launch_bounds__(256) void k1_gates_qn(
    const float* __restrict__ q, const float* __restrict__ wg,
    const float* __restrict__ g, const float* __restrict__ bln,
    float* __restrict__ qn, float* __restrict__ gates) {
  int b = blockIdx.x, t = threadIdx.x;
  int w = t >> 6, lane = t & 63;
  __shared__ float r1[4], r2[4];
  __shared__ float gp[4][8];
  float v0 = q[b*CD + t], v1 = q[b*CD + 256 + t];
  float s = v0 + v1;
  #pragma unroll
  for (int m = 32; m >= 1; m >>= 1) s += __shfl_xor(s, m);
  if (lane == 0) r1[w] = s;
  __syncthreads();
  float mu = (r1[0]+r1[1]+r1[2]+r1[3]) * (1.0f/CD);
  float c0 = v0 - mu, c1 = v1 - mu;
  s = c0*c0 + c1*c1;
  #pragma unroll
  for (int m = 32; m >= 1; m >>= 1) s += __shfl_xor(s, m);
  if (lane == 0) r2[w] = s;
  float ge[CE];
  #pragma unroll
  for (int e = 0; e < CE; e++) ge[e] = v0 * wg[t*CE + e] + v1 * wg[(256+t)*CE + e];
  #pragma unroll
  for (int m = 32; m >= 1; m >>= 1) {
    #pragma unroll
    for (int e = 0; e < CE; e++) ge[e] += __shfl_xor(ge[e], m);
  }
  if (lane == 0) {
    #pragma unroll
    for (int e = 0; e < CE; e++) gp[w][e] = ge[e];
  }
  __syncthreads();
  float rstd = rsqrtf((r2[0]+r2[1]+r2[2]+r2[3]) * (1.0f/CD) + 1e-5f);
  float xn0 = c0 * rstd, xn1 = c1 * rstd;
  #pragma unroll
  for (int e = 0; e < CE; e++) {
    qn[(b*CE + e)*CD + t]       = xn0 * g[e*CD + t]       + bln[e*CD + t];
    qn[(b*CE + e)*CD + 256 + t] = xn1 * g[e*CD + 256 + t] + bln[e*CD + 256 + t];
  }
  if (t == 0) {
    float logit[CE];
    float m = -1e30f;
    #pragma unroll
    for (int e = 0; e < CE; e++) {
      logit[e] = gp[0][e] + gp[1][e] + gp[2][e] + gp[3][e];
      m = fmaxf(m, logit[e]);
    }
    float ssum = 0.f, ex[CE];
    #pragma unroll
    for (int e = 0; e < CE; e++) { ex[e] = __expf(logit[e] - m); ssum += ex[e]; }
    #pragma unroll
    for (int e = 0; e < CE; e++) gates[b*CE + e] = ex[e] / ssum;
  }
}

// Streaming split-K GEMV16: out_partial[kc][b][e][n] = sum_k X[b,e,k]*W[e,k,n]
template<int KC>
__global__ __launch_bounds__(256) void gstream(
    const float* __restrict__ X, int xb_, int xe_,
    const float* __restrict__ W, size_t we_, int ldw,
    float* __restrict__ P, int ntiles, size_t pc_, int pb_, int pe_) {
  int e = blockIdx.y;
  int nt = blockIdx.x % ntiles, kc = blockIdx.x / ntiles;
  int n0 = nt * 64, k0 = kc * KC;
  __shared__ float xs[KC][16];
  __shared__ float red[16][64];
  int t = threadIdx.x;
  for (int idx = t; idx < KC * 16; idx += 256) {
    int k = idx >> 4, b = idx & 15;
    xs[k][b] = X[(size_t)b * xb_ + (size_t)e * xe_ + k0 + k];
  }
  __syncthreads();
  int n = t & 63, kq = t >> 6;
  float acc[16] = {};
  const float* Wp = W + (size_t)e * we_ + (size_t)k0 * ldw + n0 + n;
  #pragma unroll 4
  for (int k = kq * (KC/4); k < (kq+1) * (KC/4); k++) {
    float w = Wp[(size_t)k * ldw];
    const float4* xp = reinterpret_cast<const float4*>(xs[k]);
    float4 x0 = xp[0], x1 = xp[1], x2 = xp[2], x3 = xp[3];
    acc[0]  += x0.x*w; acc[1]  += x0.y*w; acc[2]  += x0.z*w; acc[3]  += x0.w*w;
    acc[4]  += x1.x*w; acc[5]  += x1.y*w; acc[6]  += x1.z*w; acc[7]  += x1.w*w;
    acc[8]  += x2.x*w; acc[9]  += x2.y*w; acc[10] += x2.z*w; acc[11] += x2.w*w;
    acc[12] += x3.x*w; acc[13] += x3.y*w; acc[14] += x3.z*w; acc[15] += x3.w*w;
  }
  if (kq == 0) {
    #pragma unroll
    for (int b = 0; b < 16; b++) red[b][n] = acc[b];
  }
  __syncthreads();
  #pragma unroll
  for (int qq = 1; qq < 4; qq++) {
    if (kq == qq) {
      #pragma unroll
      for (int b = 0; b < 16; b++) red[b][n] += acc[b];
    }
    __syncthreads();
  }
  #pragma unroll
  for (int i = 0; i < 4; i++) {
    int b = kq*4 + i;
    P[(size_t)kc*pc_ + (size_t)b*pb_ + (size_t)e*pe_ + n0 + n] = red[b][n];
  }
}

// Wv variant: sums the 4 k6 partials during staging, then streams Wv column block.
__global__ __launch_bounds__(256) void gstream_v(
    const float* __restrict__ rp, const float* __restrict__ Wv,
    float* __restrict__ P) {
  int eh = blockIdx.y, kc = blockIdx.x;
  int e = eh >> 3, h = eh & 7;
  int k0 = kc * 64;
  __shared__ float xs[64][20];
  __shared__ float red[16][64];
  int t = threadIdx.x;
  for (int idx = t; idx < 64 * 16; idx += 256) {
    int k = idx & 63, b = idx >> 6;   // k fastest -> coalesced
    float s = 0.f;
    #pragma unroll
    for (int c = 0; c < 4; c++)
      s += rp[(size_t)c*(CB*CEH*CD) + ((size_t)(b*CEH + eh))*CD + k0 + k];
    xs[k][b] = s;
  }
  __syncthreads();
  int n = t & 63, kq = t >> 6;
  float acc[16] = {};
  const float* Wp = Wv + (size_t)e*CD*CD + (size_t)k0*CD + h*64 + n;
  #pragma unroll 4
  for (int k = kq*16; k < kq*16 + 16; k++) {
    float w = Wp[(size_t)k * CD];
    const float4* xp = reinterpret_cast<const float4*>(&xs[k][0]);
    float4 x0 = xp[0], x1 = xp[1], x2 = xp[2], x3 = xp[3];
    acc[0]  += x0.x*w; acc[1]  += x0.y*w; acc[2]  += x0.z*w; acc[3]  += x0.w*w;
    acc[4]  += x1.x*w; acc[5]  += x1.y*w; acc[6]  += x1.z*w; acc[7]  += x1.w*w;
    acc[8]  += x2.x*w; acc[9]  += x2.y*w; acc[10] += x2.z*w; acc[11] += x2.w*w;
    acc[12] += x3.x*w; acc[13] += x3.y*w; acc[14] += x3.z*w; acc[15] += x3.w*w;
  }
  if (kq == 0) { 
    #pragma unroll
    for (int b = 0; b < 16; b++) red[b][n] = acc[b]; }
  __syncthreads();
  #pragma unroll
  for (int qq = 1; qq < 4; qq++) {
    if (kq == qq) {
      #pragma unroll
      for (int b = 0; b < 16; b++) red[b][n] += acc[b];
    }
    __syncthreads();
  }
  #pragma unroll
  for (int i = 0; i < 4; i++) {
    int b = kq*4 + i;
    P[(size_t)kc*65536 + (size_t)b*4096 + (size_t)eh*64 + n] = red[b][n];
  }
}

// Wo stream: staging computes attn = sum(Pv partials) + bv, then streams Wo.
__global__ __launch_bounds__(256) void gstream_wo(
    const float* __restrict__ Pv, const float* __restrict__ bv,
    const float* __restrict__ Wo, float* __restrict__ P) {
  int e = blockIdx.y;
  int nt = blockIdx.x % 8, kc = blockIdx.x / 8;
  int n0 = nt * 64, k0 = kc * 64;
  __shared__ float xs[64][20];
  __shared__ float red[16][64];
  int t = threadIdx.x;
  for (int idx = t; idx < 64 * 16; idx += 256) {
    int k = idx & 63, b = idx >> 6;   // k fastest -> coalesced
    float s = bv[e*CD + k0 + k];
    #pragma unroll
    for (int c = 0; c < 8; c++)
      s += Pv[(size_t)c*65536 + (size_t)b*4096 + e*512 + k0 + k];
    xs[k][b] = s;
  }
  __syncthreads();
  int n = t & 63, kq = t >> 6;
  float acc[16] = {};
  const float* Wp = Wo + (size_t)e*CD*CD + (size_t)k0*CD + n0 + n;
  #pragma unroll 4
  for (int k = kq*16; k < kq*16 + 16; k++) {
    float w = Wp[(size_t)k * CD];
    const float4* xp = reinterpret_cast<const float4*>(&xs[k][0]);
    float4 x0 = xp[0], x1 = xp[1], x2 = xp[2], x3 = xp[3];
    acc[0]  += x0.x*w; acc[1]  += x0.y*w; acc[2]  += x0.z*w; acc[3]  += x0.w*w;
    acc[4]  += x1.x*w; acc[5]  += x1.y*w; acc[6]  += x1.z*w; acc[7]  += x1.w*w;
    acc[8]  += x2.x*w; acc[9]  += x2.y*w; acc[10] += x2.z*w; acc[11] += x2.w*w;
    acc[12] += x3.x*w; acc[13] += x3.y*w; acc[14] += x3.z*w; acc[15] += x3.w*w;
  }
  if (kq == 0) {
    #pragma unroll
    for (int b = 0; b < 16; b++) red[b][n] = acc[b]; }
  __syncthreads();
  #pragma unroll
  for (int qq = 1; qq < 4; qq++) {
    if (kq == qq) {
      #pragma unroll
      for (int b = 0; b < 16; b++) red[b][n] += acc[b];
    }
    __syncthreads();
  }
  #pragma unroll
  for (int i = 0; i < 4; i++) {
    int b = kq*4 + i;
    P[(size_t)kc*65536 + (size_t)b*4096 + (size_t)e*512 + n0 + n] = red[b][n];
  }
}

// W2 stream: staging computes h = gelu(sum(4 FFN1 partials) + b1), streams W2.
__global__ __launch_bounds__(256) void gstream_w2(
    const float* __restrict__ P1, const float* __restrict__ b1,
    const float* __restrict__ W2, float* __restrict__ Pout) {
  int e = blockIdx.y;
  int nt = blockIdx.x % 8, kc = blockIdx.x / 8;
  int n0 = nt * 64, k0 = kc * 256;
  __shared__ float xs[256][20];
  __shared__ float red[16][64];
  int t = threadIdx.x;
  for (int idx = t; idx < 256 * 16; idx += 256) {
    int k = idx & 255, b = idx >> 8;   // k fastest -> coalesced
    float v = b1[e*CF + k0 + k];
    #pragma unroll
    for (int c = 0; c < 4; c++)
      v += P1[(size_t)c*262144 + (size_t)b*16384 + e*2048 + k0 + k];
    xs[k][b] = 0.5f*v*(1.f + erff(v*0.70710678118f));
  }
  __syncthreads();
  int n = t & 63, kq = t >> 6;
  float acc[16] = {};
  const float* Wp = W2 + (size_t)e*CF*CD + (size_t)k0*CD + n0 + n;
  #pragma unroll 4
  for (int k = kq*64; k < kq*64 + 64; k++) {
    float w = Wp[(size_t)k * CD];
    const float4* xp = reinterpret_cast<const float4*>(&xs[k][0]);
    float4 x0 = xp[0], x1 = xp[1], x2 = xp[2], x3 = xp[3];
    acc[0]  += x0.x*w; acc[1]  += x0.y*w; acc[2]  += x0.z*w; acc[3]  += x0.w*w;
    acc[4]  += x1.x*w; acc[5]  += x1.y*w; acc[6]  += x1.z*w; acc[7]  += x1.w*w;
    acc[8]  += x2.x*w; acc[9]  += x2.y*w; acc[10] += x2.z*w; acc[11] += x2.w*w;
    acc[12] += x3.x*w; acc[13] += x3.y*w; acc[14] += x3.z*w; acc[15] += x3.w*w;
  }
  if (kq == 0) {
    #pragma unroll
    for (int b = 0; b < 16; b++) red[b][n] = acc[b]; }
  __syncthreads();
  #pragma unroll
  for (int qq = 1; qq < 4; qq++) {
    if (kq == qq) {
      #pragma unroll
      for (int b = 0; b < 16; b++) red[b][n] += acc[b];
    }
    __syncthreads();
  }
  #pragma unroll
  for (int i = 0; i < 4; i++) {
    int b = kq*4 + i;
    Pout[(size_t)kc*65536 + (size_t)b*4096 + (size_t)e*512 + n0 + n] = red[b][n];
  }
}

// x = q + sum partials + bo; then LayerNorm -> xo (writes both)
__global__ __launch_bounds__(512) void comb_o_lno(
    const float* __restrict__ P, const float* __restrict__ bo,
    const float* __restrict__ q, const float* __restrict__ g,
    const float* __restrict__ bb, float* __restrict__ xb,
    float* __restrict__ xo) {
  int be = blockIdx.x, b = be >> 3, e = be & 7, t = threadIdx.x;
  float v = q[b*CD + t] + bo[e*CD + t];
  #pragma unroll
  for (int c = 0; c < 8; c++)
    v += P[(size_t)c*65536 + (size_t)b*4096 + e*512 + t];
  xb[be*CD + t] = v;
  __shared__ float red[512];
  red[t] = v; __syncthreads();
  for (int s = 256; s > 0; s >>= 1) { if (t < s) red[t] += red[t+s]; __syncthreads(); }
  float mu = red[0] * (1.0f/CD); __syncthreads();
  float c0 = v - mu;
  red[t] = c0*c0; __syncthreads();
  for (int s = 256; s > 0; s >>= 1) { if (t < s) red[t] += red[t+s]; __syncthreads(); }
  float rstd = rsqrtf(red[0] * (1.0f/CD) + 1e-5f);
  xo[be*CD + t] = c0*rstd*g[e*CD + t] + bb[e*CD + t];
}

// yout = sum partials + b2 + x; gated mixture -> fused, gtout
__global__ __launch_bounds__(512) void comb_ffn2_final(
    const float* __restrict__ P, const float* __restrict__ b2,
    const float* __restrict__ xb, const float* __restrict__ gates,
    const float* __restrict__ entp, float* __restrict__ yout,
    float* __restrict__ fused, float* __restrict__ gtout) {
  int b = blockIdx.x, t = threadIdx.x;
  __shared__ float gt_s[CE];
  if (t < CE) {
    float Hs = 0.f;
    #pragma unroll
    for (int c = 0; c < 8; c++) Hs += entp[(b*CE + t)*8 + c];
    gt_s[t] = gates[b*CE + t] * __expf(-0.5f * Hs);
  }
  __syncthreads();
  if (t == 0) {
    float s = 0.f;
    for (int e = 0; e < CE; e++) s += gt_s[e];
    s += 1e-9f;
    for (int e = 0; e < CE; e++) gt_s[e] /= s;
  }
  __syncthreads();
  float acc = 0.f;
  #pragma unroll
  for (int e = 0; e < CE; e++) {
    float y = b2[e*CD + t] + xb[(b*CE + e)*CD + t];
    #pragma unroll
    for (int c = 0; c < 8; c++)
      y += P[(size_t)c*65536 + (size_t)b*4096 + e*512 + t];
    yout[(b*CE + e)*CD + t] = y;
    acc += gt_s[e] * y;
  }
  fused[b*CD + t] = acc;  // ALPHA = 1.0 -> fused == mixture
  if (t < CE) gtout[b*CE + t] = gt_s[t];
}

// k4: wk_eff = Wk_slice^T @ qh (qh combined from Wq partials inline, coalesced) -> bf16 wkh;
// dt==0 block also emits sbias[b][e][h] = qh_hslice . bk_hslice.
__global__ __launch_bounds__(256) void k4_wkeff(
    const float* __restrict__ Wk, const float* __restrict__ Pq,
    const float* __restrict__ bq, const float* __restrict__ bk,
    __bf16* __restrict__ wkh, float* __restrict__ sbias) {
  int e = blockIdx.y;
  int h = blockIdx.x >> 3, dt = blockIdx.x & 7;
  int d0 = dt * 64;
  __shared__ float wks[64][65];   // [c][d]
  __shared__ float qs[64][20];    // [c][b] (pad 20: 16B-aligned rows)
  __shared__ float red[16][64];
  int t = threadIdx.x;
  for (int idx = t; idx < 64*64; idx += 256) {
    int c = idx & 63, d = idx >> 6;
    wks[c][d] = Wk[(size_t)e*CD*CD + (size_t)(d0+d)*CD + h*64 + c];
  }
  for (int idx = t; idx < 64*16; idx += 256) {
    int c = idx & 63, b = idx >> 6;   // c fastest -> coalesced partial reads
    float s = bq[e*CD + h*64 + c];
    #pragma unroll
    for (int cc = 0; cc < 8; cc++)
      s += Pq[(size_t)cc*65536 + (size_t)b*4096 + e*512 + h*64 + c];
    qs[c][b] = s;
  }
  __syncthreads();
  if (dt == 0) {
    int bb = t >> 4, ii = t & 15;
    float p = 0.f;
    #pragma unroll
    for (int j = 0; j < 4; j++)
      p += qs[ii*4 + j][bb] * bk[e*CD + h*64 + ii*4 + j];
    p += __shfl_xor(p, 1);
    p += __shfl_xor(p, 2);
    p += __shfl_xor(p, 4);
    p += __shfl_xor(p, 8);
    if (ii == 0) sbias[bb*CEH + e*8 + h] = p;
  }
  int d = t & 63, cq = t >> 6;
  float acc[16] = {};
  #pragma unroll 4
  for (int c = cq*16; c < cq*16 + 16; c++) {
    float w = wks[c][d];
    const float4* xp = reinterpret_cast<const float4*>(&qs[c][0]);
    float4 x0 = xp[0], x1 = xp[1], x2 = xp[2], x3 = xp[3];
    acc[0]  += x0.x*w; acc[1]  += x0.y*w; acc[2]  += x0.z*w; acc[3]  += x0.w*w;
    acc[4]  += x1.x*w; acc[5]  += x1.y*w; acc[6]  += x1.z*w; acc[7]  += x1.w*w;
    acc[8]  += x2.x*w; acc[9]  += x2.y*w; acc[10] += x2.z*w; acc[11] += x2.w*w;
    acc[12] += x3.x*w; acc[13] += x3.y*w; acc[14] += x3.z*w; acc[15] += x3.w*w;
  }
  if (cq == 0) { 
    #pragma unroll
    for (int b = 0; b < 16; b++) red[b][d] = acc[b]; }
  __syncthreads();
  #pragma unroll
  for (int qq = 1; qq < 4; qq++) {
    if (cq == qq) {
      #pragma unroll
      for (int b = 0; b < 16; b++) red[b][d] += acc[b];
    }
    __syncthreads();
  }
  int eh = e*8 + h;
  #pragma unroll
  for (int i = 0; i < 4; i++) {
    int b = cq*4 + i;
    wkh[((size_t)(b*CEH + eh))*CD + d0 + d] = (__bf16)red[b][d];
  }
}

// sc[b][eh][l] = (ret[b][l][:]·wk_eff[b][eh][:] + qh·bk)/8 via bf16 MFMA.
// global_load_lds double-buffered staging (BK=64), XOR-swizzled source. (R12 proven version)
__global__ __launch_bounds__(256) void k5_mfma(
    const float* __restrict__ ret, const __bf16* __restrict__ wkh,
    const float* __restrict__ sbias, float* __restrict__ sc,
    float* __restrict__ lmax, float* __restrict__ lsum) {
  int b = blockIdx.y, lt = blockIdx.x, t = threadIdx.x;
  int w = t >> 6, lane = t & 63;
  int lnlo = lane & 15, lnhi = lane >> 4;
  int lh = w & 1, ehh = w >> 1;
  int l0blk = lt*32;
  int ehbase = ehh*32;
  __shared__ __align__(16) char ldsbuf[32768];
  f32x4 acc[2];
  acc[0] = (f32x4){0.f,0.f,0.f,0.f};
  acc[1] = (f32x4){0.f,0.f,0.f,0.f};
  const float*  retb  = ret + (size_t)(b*CL + l0blk)*CD;
  const __bf16* wkhb  = wkh + (size_t)b*CEH*CD;

  int rs0 = t,        rl0 = rs0 >> 4, rg0 = ((rs0 & 15) ^ (rl0 & 15)) << 2;
  int rs1 = t + 256,  rl1 = rs1 >> 4, rg1 = ((rs1 & 15) ^ (rl1 & 15)) << 2;
  int ws0 = t,        we0 = ws0 >> 3, wg0 = ((ws0 & 7) ^ (we0 & 7)) << 3;
  int ws1 = t + 256,  we1 = ws1 >> 3, wg1 = ((ws1 & 7) ^ (we1 & 7)) << 3;

  #define K5_STAGE(bufi, kt) do {                                          \
    char* rB = ldsbuf + (bufi)*8192;                                       \
    char* wB = ldsbuf + 16384 + (bufi)*8192;                               \
    int dofs = (kt)*64;                                                    \
    GLL16(retb + (size_t)rl0*CD + dofs + rg0, rB + rs0*16);                \
    GLL16(retb + (size_t)rl1*CD + dofs + rg1, rB + rs1*16);                \
    GLL16(wkhb + (size_t)we0*CD + dofs + wg0, wB + ws0*16);                \
    GLL16(wkhb + (size_t)we1*CD + dofs + wg1, wB + ws1*16);                \
  } while (0)

  K5_STAGE(0, 0);
  __syncthreads();
  #pragma unroll
  for (int kt = 0; kt < 8; kt++) {
    int cur = kt & 1;
    if (kt < 7) K5_STAGE(cur ^ 1, kt + 1);
    const char* rB = ldsbuf + cur*8192;
    const char* wB = ldsbuf + 16384 + cur*8192;
    #pragma unroll
    for (int sub = 0; sub < 2; sub++) {
      int g0 = (sub*8 + lnhi*2 + 0) ^ lnlo;
      int g1 = (sub*8 + lnhi*2 + 1) ^ lnlo;
      float4 f0 = *reinterpret_cast<const float4*>(rB + (lh*16 + lnlo)*256 + g0*16);
      float4 f1 = *reinterpret_cast<const float4*>(rB + (lh*16 + lnlo)*256 + g1*16);
      bf16x8 bfrag;
      bfrag[0]=(__bf16)f0.x; bfrag[1]=(__bf16)f0.y; bfrag[2]=(__bf16)f0.z; bfrag[3]=(__bf16)f0.w;
      bfrag[4]=(__bf16)f1.x; bfrag[5]=(__bf16)f1.y; bfrag[6]=(__bf16)f1.z; bfrag[7]=(__bf16)f1.w;
      int ga = (sub*4 + lnhi) ^ (lnlo & 7);
      bf16x8 a0 = *reinterpret_cast<const bf16x8*>(wB + (ehbase + 0*16 + lnlo)*128 + ga*16);
      bf16x8 a1 = *reinterpret_cast<const bf16x8*>(wB + (ehbase + 1*16 + lnlo)*128 + ga*16);
      acc[0] = __builtin_amdgcn_mfma_f32_16x16x32_bf16(a0, bfrag, acc[0], 0, 0, 0);
      acc[1] = __builtin_amdgcn_mfma_f32_16x16x32_bf16(a1, bfrag, acc[1], 0, 0, 0);
    }
    __syncthreads();
  }
  #undef K5_STAGE

  int strip = lt*2 + lh;
  int l = l0blk + lh*16 + lnlo;
  #pragma unroll
  for (int et = 0; et < 2; et++) {
    #pragma unroll
    for (int i = 0; i < 4; i++) {
      int eh = ehbase + et*16 + lnhi*4 + i;
      float v = acc[et][i]*0.125f + sbias[b*CEH + eh]*0.125f;
      sc[((size_t)(b*CEH + eh))*CL + l] = v;
      float m = v;
      m = fmaxf(m, __shfl_xor(m, 1));
      m = fmaxf(m, __shfl_xor(m, 2));
      m = fmaxf(m, __shfl_xor(m, 4));
      m = fmaxf(m, __shfl_xor(m, 8));
      float s = __expf(v - m);
      s += __shfl_xor(s, 1);
      s += __shfl_xor(s, 2);
      s += __shfl_xor(s, 4);
      s += __shfl_xor(s, 8);
      if (lnlo == et*4 + i) {
        lmax[((size_t)(b*CEH + eh))*128 + strip] = m;
        lsum[((size_t)(b*CEH + eh))*128 + strip] = s;
      }
    }
  }
}

// normalize sc -> bf16 probs pb; row softmax stats reduced inline from lmax/lsum;
// entropy partials per (b,e,lchunk)
__global__ __launch_bounds__(256) void k5n(
    const float* __restrict__ sc, const float* __restrict__ lmax,
    const float* __restrict__ lsum, __bf16* __restrict__ pb,
    float* __restrict__ entp) {
  int e = blockIdx.x, b = blockIdx.y, lc = blockIdx.z, t = threadIdx.x;
  __shared__ float M_s[8], I_s[8];
  {
    int g = t >> 5, lane = t & 31;
    int eh = e*8 + g;
    const float* lm = lmax + ((size_t)(b*CEH + eh))*128;
    const float* ls = lsum + ((size_t)(b*CEH + eh))*128;
    float M = -1e30f, S = 0.f;
    #pragma unroll
    for (int j = 0; j < 4; j++) {
      float m2 = lm[lane + j*32], s2 = ls[lane + j*32];
      float Mn = fmaxf(M, m2);
      S = S*__expf(M - Mn) + s2*__expf(m2 - Mn);
      M = Mn;
    }
    #pragma unroll
    for (int mask = 16; mask >= 1; mask >>= 1) {
      float Mo = __shfl_xor(M, mask), So = __shfl_xor(S, mask);
      float Mn = fmaxf(M, Mo);
      S = S*__expf(M - Mn) + So*__expf(Mo - Mn);
      M = Mn;
    }
    if (lane == 0) { M_s[g] = M; I_s[g] = 1.f / S; }
  }
  __syncthreads();
  int l = lc*256 + t;
  float pbav = 0.f;
  #pragma unroll
  for (int h = 0; h < 8; h++) {
    size_t ix = ((size_t)(b*CEH + e*8 + h))*CL + l;
    float p = __expf(sc[ix] - M_s[h]) * I_s[h];
    pb[ix] = (__bf16)p;
    pbav += p;
  }
  pbav = fmaxf(pbav*0.125f, 1e-12f);
  float ent = -pbav * __logf(pbav);
  __shared__ float red[256];
  red[t] = ent; __syncthreads();
  for (int s = 128; s > 0; s >>= 1) { if (t < s) red[t] += red[t+s]; __syncthreads(); }
  if (t == 0) entp[(b*CE + e)*8 + lc] = red[0];
}

// reff partial[lc][b][eh][d] = sum_{l in 512-chunk} P[b][eh][l] * ret[b][l][d] via bf16 MFMA.
// 8 d-tiles x 4 L-chunks per b; ping-pong LDS + register prefetch, 16 K-steps.
__global__ __launch_bounds__(256) void k6_mfma(
    const __bf16* __restrict__ pb, const float* __restrict__ ret,
    float* __restrict__ part) {
  int b = blockIdx.y;
  int dt = blockIdx.x & 7, lc = blockIdx.x >> 3;
  int d0 = dt*64, l0 = lc*512;
  int t = threadIdx.x, w = t >> 6, lane = t & 63;
  int lnlo = lane & 15, lnhi = lane >> 4;
  __shared__ __bf16 Bs[2][64][40];   // [buf][d][l] transposed ret tile
  f32x4 acc[4];
  #pragma unroll
  for (int et = 0; et < 4; et++) acc[et] = (f32x4){0.f,0.f,0.f,0.f};
  const __bf16* pbb = pb + ((size_t)(b*CEH) + lnlo)*CL + l0 + lnhi*8;
  int srow = t & 31, scol = (t >> 5)*8;
  const float* retb = ret + ((size_t)(b*CL) + l0 + srow)*CD + d0 + scol;
  float4 v0 = *reinterpret_cast<const float4*>(retb);
  float4 v1 = *reinterpret_cast<const float4*>(retb + 4);
  bf16x8 ap0 = *reinterpret_cast<const bf16x8*>(pbb);
  bf16x8 ap1 = *reinterpret_cast<const bf16x8*>(pbb + (size_t)16*CL);
  bf16x8 ap2 = *reinterpret_cast<const bf16x8*>(pbb + (size_t)32*CL);
  bf16x8 ap3 = *reinterpret_cast<const bf16x8*>(pbb + (size_t)48*CL);
  #pragma unroll
  for (int kt = 0; kt < 16; kt++) {
    int cur = kt & 1;
    Bs[cur][scol+0][srow] = (__bf16)v0.x; Bs[cur][scol+1][srow] = (__bf16)v0.y;
    Bs[cur][scol+2][srow] = (__bf16)v0.z; Bs[cur][scol+3][srow] = (__bf16)v0.w;
    Bs[cur][scol+4][srow] = (__bf16)v1.x; Bs[cur][scol+5][srow] = (__bf16)v1.y;
    Bs[cur][scol+6][srow] = (__bf16)v1.z; Bs[cur][scol+7][srow] = (__bf16)v1.w;
    bf16x8 an0, an1, an2, an3;
    if (kt < 15) {
      v0 = *reinterpret_cast<const float4*>(retb + (size_t)(kt+1)*32*CD);
      v1 = *reinterpret_cast<const float4*>(retb + (size_t)(kt+1)*32*CD + 4);
      an0 = *reinterpret_cast<const bf16x8*>(pbb + (kt+1)*32);
      an1 = *reinterpret_cast<const bf16x8*>(pbb + (size_t)16*CL + (kt+1)*32);
      an2 = *reinterpret_cast<const bf16x8*>(pbb + (size_t)32*CL + (kt+1)*32);
      an3 = *reinterpret_cast<const bf16x8*>(pbb + (size_t)48*CL + (kt+1)*32);
    }
    __syncthreads();
    bf16x8 bfrag = *reinterpret_cast<const bf16x8*>(&Bs[cur][w*16 + lnlo][lnhi*8]);
    acc[0] = __builtin_amdgcn_mfma_f32_16x16x32_bf16(ap0, bfrag, acc[0], 0, 0, 0);
    acc[1] = __builtin_amdgcn_mfma_f32_16x16x32_bf16(ap1, bfrag, acc[1], 0, 0, 0);
    acc[2] = __builtin_amdgcn_mfma_f32_16x16x32_bf16(ap2, bfrag, acc[2], 0, 0, 0);
    acc[3] = __builtin_amdgcn_mfma_f32_16x16x32_bf16(ap3, bfrag, acc[3], 0, 0, 0);
    if (kt < 15) { ap0 = an0; ap1 = an1; ap2 = an2; ap3 = an3; }
    __syncthreads();
  }
  float* dst = part + (size_t)lc*(CB*CEH*CD);
  int d = d0 + w*16 + lnlo;
  #pragma unroll
  for (int et = 0; et < 4; et++) {
    #pragma unroll
    for (int i = 0; i < 4; i++) {
      int eh = et*16 + lnhi*4 + i;
      dst[((size_t)(b*CEH + eh))*CD + d] = acc[et][i];
    }
  }
}

extern "C" void kernel_launch(void* const* d_in, const int* in_sizes, int n_in,
                              void* d_out, int out_size, void* d_ws, size_t ws_size,
                              hipStream_t stream) {
  const float* q    = (const float*)d_in[0];
  const float* ret  = (const float*)d_in[1];
  const float* wg   = (const float*)d_in[2];
  const float* lnqg = (const float*)d_in[3];
  const float* lnqb = (const float*)d_in[4];
  const float* Wq   = (const float*)d_in[5];
  const float* bq   = (const float*)d_in[6];
  const float* Wk   = (const float*)d_in[7];
  const float* bk   = (const float*)d_in[8];
  const float* Wv   = (const float*)d_in[9];
  const float* bv   = (const float*)d_in[10];
  const float* Wo   = (const float*)d_in[11];
  const float* bo   = (const float*)d_in[12];
  const float* lnog = (const float*)d_in[13];
  const float* lnob = (const float*)d_in[14];
  const float* W1   = (const float*)d_in[15];
  const float* b1   = (const float*)d_in[16];
  const float* W2   = (const float*)d_in[17];
  const float* b2   = (const float*)d_in[18];

  float* ws = (float*)d_ws;
  float* fused = (float*)d_out;
  float* yout  = fused + CB*CD;
  float* gtout = yout + CB*CE*CD;

  float* gates = ws + WS_GATES;
  float* qn    = ws + WS_QN;
  float* sbias = ws + WS_SBIAS;
  __bf16* wkh  = (__bf16*)(ws + WS_WK);
  float* sc    = ws + WS_SC;
  float* part0 = ws + WS_PART;
  float* part1 = ws + WS_PART1;
  float* entp  = ws + WS_ENT;
  float* xb    = ws + WS_X;
  float* xo    = ws + WS_XO;
  float* rpart = ws + WS_RP;
  __bf16* pb16 = (__bf16*)(ws + WS_PB16);
  float* lmax  = rpart;                      // dead before k6_mfma writes rpart
  float* lsum  = rpart + CB*CEH*128;

  k1_gates_qn<<<CB, 256, 0, stream>>>(q, wg, lnqg, lnqb, qn, gates);
  // qh partials = qn @ Wq : K=512 (8 chunks of 64), N=512 (8 tiles)
  gstream<64><<<dim3(64, CE), 256, 0, stream>>>(qn, CE*CD, CD, Wq, (size_t)CD*CD, CD,
                                                part0, 8, 65536, CE*CD, CD);
  // wk_eff (bf16) from Wk and combined qh; dt==0 blocks emit sbias
  k4_wkeff<<<dim3(64, CE), 256, 0, stream>>>(Wk, part0, bq, bk, wkh, sbias);
  k5_mfma<<<dim3(64, CB), 256, 0, stream>>>(ret, wkh, sbias, sc, lmax, lsum);
  k5n<<<dim3(CE, CB, 8), 256, 0, stream>>>(sc, lmax, lsum, pb16, entp);
  k6_mfma<<<dim3(32, CB), 256, 0, stream>>>(pb16, ret, rpart);
  // attn partials (over d-chunks) from reff(=sum 4 rpart) @ Wv
  gstream_v<<<dim3(8, CEH), 256, 0, stream>>>(rpart, Wv, part1);
  // x-partials: (attn = sum part1 + bv) @ Wo
  gstream_wo<<<dim3(64, CE), 256, 0, stream>>>(part1, bv, Wo, part0);
  comb_o_lno<<<CB*CE, 512, 0, stream>>>(part0, bo, q, lnog, lnob, xb, xo);
  // FFN1 partials = xo @ W1 : K=512 (4 chunks of 128), N=2048 (32 tiles)
  gstream<128><<<dim3(128, CE), 256, 0, stream>>>(xo, CE*CD, CD, W1, (size_t)CD*CF, CF,
                                                  part0, 32, 262144, CE*CF, CF);
  // y-partials = gelu(FFN1) @ W2 : staging applies bias+GELU (coalesced); -> rpart
  gstream_w2<<<dim3(64, CE), 256, 0, stream>>>(part0, b1, W2, rpart);
  comb_ffn2_final<<<CB, 512, 0, stream>>>(rpart, b2, xb, gates, entp, yout, fused, gtout);
}

// Round 15
// 119.049 us; speedup vs baseline: 1.0530x; 1.0094x over previous
//
#include <hip/hip_runtime.h>
#include <math.h>

#define CB 16
#define CL 2048
#define CD 512
#define CE 8
#define CH 8
#define CEH 64
#define CF 2048

typedef __bf16 bf16x8 __attribute__((ext_vector_type(8)));
typedef float f32x4 __attribute__((ext_vector_type(4)));

#define GLL16(srcp, dstp) __builtin_amdgcn_global_load_lds( \
    (const __attribute__((address_space(1))) unsigned int*)(srcp), \
    (__attribute__((address_space(3))) unsigned int*)(dstp), 16, 0, 0)

// ws layout (float offsets)
#define WS_GATES 0
#define WS_XN    (WS_GATES + CB*CE)
#define WS_QN    (WS_XN + CB*CD)
#define WS_QH    (WS_QN + CB*CE*CD)
#define WS_SBIAS (WS_QH + CB*CE*CD)
#define WS_WK    (WS_SBIAS + CB*CE*CH)          /* bf16 wkh [b][eh][d] */
#define WS_SC    (WS_WK + CB*CEH*CD)            /* fp32 sc [b][eh][l]; partials alias (liveness disjoint) */
#define WS_PART  WS_SC
#define WS_PART1 (WS_PART + 524288)
#define WS_ENT   (WS_SC + CB*CL*CEH)            /* [b][e][8] chunk partials */
#define WS_ATTN  (WS_ENT + CB*CE*8)
#define WS_X     (WS_ATTN + CB*CE*CD)
#define WS_XO    (WS_X + CB*CE*CD)
#define WS_HB    (WS_XO + CB*CE*CD)
#define WS_RP    (WS_HB + CB*CE*CF)             /* 4 * CB*CEH*CD fp32 partials; lmax/lsum alias head; W2 partials reuse */
#define WS_PB16  (WS_RP + 8*CB*CEH*CD)          /* bf16 probs [b][eh][l] */

// Wq stream with fused query-LayerNorm staging: per block, recompute the 16
// per-b LN stats (L2-cached reads), stage qn = xn*g + bln on the fly, then
// stream the Wq column block. Output: qh partials.
__global__ __launch_bounds__(256) void gstream_wq(
    const float* __restrict__ q, const float* __restrict__ g,
    const float* __restrict__ bln, const float* __restrict__ W,
    float* __restrict__ P) {
  int e = blockIdx.y;
  int nt = blockIdx.x % 8, kc = blockIdx.x / 8;
  int n0 = nt * 64, k0 = kc * 64;
  __shared__ float xs[64][20];
  __shared__ float red[16][64];
  __shared__ float muS[16], rsS[16];
  int t = threadIdx.x;
  {
    int b = t >> 4, j = t & 15;
    float s1 = 0.f, s2 = 0.f;
    const float* qb = q + b*CD + j*32;
    #pragma unroll
    for (int i = 0; i < 32; i++) { float v = qb[i]; s1 += v; s2 += v*v; }
    #pragma unroll
    for (int m = 1; m <= 8; m <<= 1) { s1 += __shfl_xor(s1, m); s2 += __shfl_xor(s2, m); }
    if (j == 0) {
      float mu = s1 * (1.0f/CD);
      float var = s2 * (1.0f/CD) - mu*mu;
      muS[b] = mu;
      rsS[b] = rsqrtf(var + 1e-5f);
    }
  }
  __syncthreads();
  for (int idx = t; idx < 64*16; idx += 256) {
    int k = idx & 63, b = idx >> 6;   // k fastest -> coalesced
    xs[k][b] = (q[b*CD + k0 + k] - muS[b]) * rsS[b] * g[e*CD + k0 + k] + bln[e*CD + k0 + k];
  }
  __syncthreads();
  int n = t & 63, kq = t >> 6;
  float acc[16] = {};
  const float* Wp = W + (size_t)e*CD*CD + (size_t)k0*CD + n0 + n;
  #pragma unroll 4
  for (int k = kq*16; k < kq*16 + 16; k++) {
    float w = Wp[(size_t)k * CD];
    const float4* xp = reinterpret_cast<const float4*>(&xs[k][0]);
    float4 x0 = xp[0], x1 = xp[1], x2 = xp[2], x3 = xp[3];
    acc[0]  += x0.x*w; acc[1]  += x0.y*w; acc[2]  += x0.z*w; acc[3]  += x0.w*w;
    acc[4]  += x1.x*w; acc[5]  += x1.y*w; acc[6]  += x1.z*w; acc[7]  += x1.w*w;
    acc[8]  += x2.x*w; acc[9]  += x2.y*w; acc[10] += x2.z*w; acc[11] += x2.w*w;
    acc[12] += x3.x*w; acc[13] += x3.y*w; acc[14] += x3.z*w; acc[15] += x3.w*w;
  }
  if (kq == 0) {
    #pragma unroll
    for (int b = 0; b < 16; b++) red[b][n] = acc[b];
  }
  __syncthreads();
  #pragma unroll
  for (int qq = 1; qq < 4; qq++) {
    if (kq == qq) {
      #pragma unroll
      for (int b = 0; b < 16; b++) red[b][n] += acc[b];
    }
    __syncthreads();
  }
  #pragma unroll
  for (int i = 0; i < 4; i++) {
    int b = kq*4 + i;
    P[(size_t)kc*65536 + (size_t)b*4096 + (size_t)e*512 + n0 + n] = red[b][n];
  }
}

// Streaming split-K GEMV16: out_partial[kc][b][e][n] = sum_k X[b,e,k]*W[e,k,n]
template<int KC>
__global__ __launch_bounds__(256) void gstream(
    const float* __restrict__ X, int xb_, int xe_,
    const float* __restrict__ W, size_t we_, int ldw,
    float* __restrict__ P, int ntiles, size_t pc_, int pb_, int pe_) {
  int e = blockIdx.y;
  int nt = blockIdx.x % ntiles, kc = blockIdx.x / ntiles;
  int n0 = nt * 64, k0 = kc * KC;
  __shared__ float xs[KC][16];
  __shared__ float red[16][64];
  int t = threadIdx.x;
  for (int idx = t; idx < KC * 16; idx += 256) {
    int k = idx >> 4, b = idx & 15;
    xs[k][b] = X[(size_t)b * xb_ + (size_t)e * xe_ + k0 + k];
  }
  __syncthreads();
  int n = t & 63, kq = t >> 6;
  float acc[16] = {};
  const float* Wp = W + (size_t)e * we_ + (size_t)k0 * ldw + n0 + n;
  #pragma unroll 4
  for (int k = kq * (KC/4); k < (kq+1) * (KC/4); k++) {
    float w = Wp[(size_t)k * ldw];
    const float4* xp = reinterpret_cast<const float4*>(xs[k]);
    float4 x0 = xp[0], x1 = xp[1], x2 = xp[2], x3 = xp[3];
    acc[0]  += x0.x*w; acc[1]  += x0.y*w; acc[2]  += x0.z*w; acc[3]  += x0.w*w;
    acc[4]  += x1.x*w; acc[5]  += x1.y*w; acc[6]  += x1.z*w; acc[7]  += x1.w*w;
    acc[8]  += x2.x*w; acc[9]  += x2.y*w; acc[10] += x2.z*w; acc[11] += x2.w*w;
    acc[12] += x3.x*w; acc[13] += x3.y*w; acc[14] += x3.z*w; acc[15] += x3.w*w;
  }
  if (kq == 0) {
    #pragma unroll
    for (int b = 0; b < 16; b++) red[b][n] = acc[b];
  }
  __syncthreads();
  #pragma unroll
  for (int qq = 1; qq < 4; qq++) {
    if (kq == qq) {
      #pragma unroll
      for (int b = 0; b < 16; b++) red[b][n] += acc[b];
    }
    __syncthreads();
  }
  #pragma unroll
  for (int i = 0; i < 4; i++) {
    int b = kq*4 + i;
    P[(size_t)kc*pc_ + (size_t)b*pb_ + (size_t)e*pe_ + n0 + n] = red[b][n];
  }
}

// Wv variant: sums the 4 k6 partials during staging, then streams Wv column block.
__global__ __launch_bounds__(256) void gstream_v(
    const float* __restrict__ rp, const float* __restrict__ Wv,
    float* __restrict__ P) {
  int eh = blockIdx.y, kc = blockIdx.x;
  int e = eh >> 3, h = eh & 7;
  int k0 = kc * 64;
  __shared__ float xs[64][20];
  __shared__ float red[16][64];
  int t = threadIdx.x;
  for (int idx = t; idx < 64 * 16; idx += 256) {
    int k = idx & 63, b = idx >> 6;   // k fastest -> coalesced
    float s = 0.f;
    #pragma unroll
    for (int c = 0; c < 4; c++)
      s += rp[(size_t)c*(CB*CEH*CD) + ((size_t)(b*CEH + eh))*CD + k0 + k];
    xs[k][b] = s;
  }
  __syncthreads();
  int n = t & 63, kq = t >> 6;
  float acc[16] = {};
  const float* Wp = Wv + (size_t)e*CD*CD + (size_t)k0*CD + h*64 + n;
  #pragma unroll 4
  for (int k = kq*16; k < kq*16 + 16; k++) {
    float w = Wp[(size_t)k * CD];
    const float4* xp = reinterpret_cast<const float4*>(&xs[k][0]);
    float4 x0 = xp[0], x1 = xp[1], x2 = xp[2], x3 = xp[3];
    acc[0]  += x0.x*w; acc[1]  += x0.y*w; acc[2]  += x0.z*w; acc[3]  += x0.w*w;
    acc[4]  += x1.x*w; acc[5]  += x1.y*w; acc[6]  += x1.z*w; acc[7]  += x1.w*w;
    acc[8]  += x2.x*w; acc[9]  += x2.y*w; acc[10] += x2.z*w; acc[11] += x2.w*w;
    acc[12] += x3.x*w; acc[13] += x3.y*w; acc[14] += x3.z*w; acc[15] += x3.w*w;
  }
  if (kq == 0) { 
    #pragma unroll
    for (int b = 0; b < 16; b++) red[b][n] = acc[b]; }
  __syncthreads();
  #pragma unroll
  for (int qq = 1; qq < 4; qq++) {
    if (kq == qq) {
      #pragma unroll
      for (int b = 0; b < 16; b++) red[b][n] += acc[b];
    }
    __syncthreads();
  }
  #pragma unroll
  for (int i = 0; i < 4; i++) {
    int b = kq*4 + i;
    P[(size_t)kc*65536 + (size_t)b*4096 + (size_t)eh*64 + n] = red[b][n];
  }
}

// Wo stream: staging computes attn = sum(Pv partials) + bv, then streams Wo.
__global__ __launch_bounds__(256) void gstream_wo(
    const float* __restrict__ Pv, const float* __restrict__ bv,
    const float* __restrict__ Wo, float* __restrict__ P) {
  int e = blockIdx.y;
  int nt = blockIdx.x % 8, kc = blockIdx.x / 8;
  int n0 = nt * 64, k0 = kc * 64;
  __shared__ float xs[64][20];
  __shared__ float red[16][64];
  int t = threadIdx.x;
  for (int idx = t; idx < 64 * 16; idx += 256) {
    int k = idx & 63, b = idx >> 6;   // k fastest -> coalesced
    float s = bv[e*CD + k0 + k];
    #pragma unroll
    for (int c = 0; c < 8; c++)
      s += Pv[(size_t)c*65536 + (size_t)b*4096 + e*512 + k0 + k];
    xs[k][b] = s;
  }
  __syncthreads();
  int n = t & 63, kq = t >> 6;
  float acc[16] = {};
  const float* Wp = Wo + (size_t)e*CD*CD + (size_t)k0*CD + n0 + n;
  #pragma unroll 4
  for (int k = kq*16; k < kq*16 + 16; k++) {
    float w = Wp[(size_t)k * CD];
    const float4* xp = reinterpret_cast<const float4*>(&xs[k][0]);
    float4 x0 = xp[0], x1 = xp[1], x2 = xp[2], x3 = xp[3];
    acc[0]  += x0.x*w; acc[1]  += x0.y*w; acc[2]  += x0.z*w; acc[3]  += x0.w*w;
    acc[4]  += x1.x*w; acc[5]  += x1.y*w; acc[6]  += x1.z*w; acc[7]  += x1.w*w;
    acc[8]  += x2.x*w; acc[9]  += x2.y*w; acc[10] += x2.z*w; acc[11] += x2.w*w;
    acc[12] += x3.x*w; acc[13] += x3.y*w; acc[14] += x3.z*w; acc[15] += x3.w*w;
  }
  if (kq == 0) {
    #pragma unroll
    for (int b = 0; b < 16; b++) red[b][n] = acc[b]; }
  __syncthreads();
  #pragma unroll
  for (int qq = 1; qq < 4; qq++) {
    if (kq == qq) {
      #pragma unroll
      for (int b = 0; b < 16; b++) red[b][n] += acc[b];
    }
    __syncthreads();
  }
  #pragma unroll
  for (int i = 0; i < 4; i++) {
    int b = kq*4 + i;
    P[(size_t)kc*65536 + (size_t)b*4096 + (size_t)e*512 + n0 + n] = red[b][n];
  }
}

// W2 stream: staging computes h = gelu(sum(4 FFN1 partials) + b1), streams W2.
__global__ __launch_bounds__(256) void gstream_w2(
    const float* __restrict__ P1, const float* __restrict__ b1,
    const float* __restrict__ W2, float* __restrict__ Pout) {
  int e = blockIdx.y;
  int nt = blockIdx.x % 8, kc = blockIdx.x / 8;
  int n0 = nt * 64, k0 = kc * 256;
  __shared__ float xs[256][20];
  __shared__ float red[16][64];
  int t = threadIdx.x;
  for (int idx = t; idx < 256 * 16; idx += 256) {
    int k = idx & 255, b = idx >> 8;   // k fastest -> coalesced
    float v = b1[e*CF + k0 + k];
    #pragma unroll
    for (int c = 0; c < 4; c++)
      v += P1[(size_t)c*262144 + (size_t)b*16384 + e*2048 + k0 + k];
    xs[k][b] = 0.5f*v*(1.f + erff(v*0.70710678118f));
  }
  __syncthreads();
  int n = t & 63, kq = t >> 6;
  float acc[16] = {};
  const float* Wp = W2 + (size_t)e*CF*CD + (size_t)k0*CD + n0 + n;
  #pragma unroll 4
  for (int k = kq*64; k < kq*64 + 64; k++) {
    float w = Wp[(size_t)k * CD];
    const float4* xp = reinterpret_cast<const float4*>(&xs[k][0]);
    float4 x0 = xp[0], x1 = xp[1], x2 = xp[2], x3 = xp[3];
    acc[0]  += x0.x*w; acc[1]  += x0.y*w; acc[2]  += x0.z*w; acc[3]  += x0.w*w;
    acc[4]  += x1.x*w; acc[5]  += x1.y*w; acc[6]  += x1.z*w; acc[7]  += x1.w*w;
    acc[8]  += x2.x*w; acc[9]  += x2.y*w; acc[10] += x2.z*w; acc[11] += x2.w*w;
    acc[12] += x3.x*w; acc[13] += x3.y*w; acc[14] += x3.z*w; acc[15] += x3.w*w;
  }
  if (kq == 0) {
    #pragma unroll
    for (int b = 0; b < 16; b++) red[b][n] = acc[b]; }
  __syncthreads();
  #pragma unroll
  for (int qq = 1; qq < 4; qq++) {
    if (kq == qq) {
      #pragma unroll
      for (int b = 0; b < 16; b++) red[b][n] += acc[b];
    }
    __syncthreads();
  }
  #pragma unroll
  for (int i = 0; i < 4; i++) {
    int b = kq*4 + i;
    Pout[(size_t)kc*65536 + (size_t)b*4096 + (size_t)e*512 + n0 + n] = red[b][n];
  }
}

// x = q + sum partials + bo; then LayerNorm -> xo (writes both)
__global__ __launch_bounds__(512) void comb_o_lno(
    const float* __restrict__ P, const float* __restrict__ bo,
    const float* __restrict__ q, const float* __restrict__ g,
    const float* __restrict__ bb, float* __restrict__ xb,
    float* __restrict__ xo) {
  int be = blockIdx.x, b = be >> 3, e = be & 7, t = threadIdx.x;
  float v = q[b*CD + t] + bo[e*CD + t];
  #pragma unroll
  for (int c = 0; c < 8; c++)
    v += P[(size_t)c*65536 + (size_t)b*4096 + e*512 + t];
  xb[be*CD + t] = v;
  __shared__ float red[512];
  red[t] = v; __syncthreads();
  for (int s = 256; s > 0; s >>= 1) { if (t < s) red[t] += red[t+s]; __syncthreads(); }
  float mu = red[0] * (1.0f/CD); __syncthreads();
  float c0 = v - mu;
  red[t] = c0*c0; __syncthreads();
  for (int s = 256; s > 0; s >>= 1) { if (t < s) red[t] += red[t+s]; __syncthreads(); }
  float rstd = rsqrtf(red[0] * (1.0f/CD) + 1e-5f);
  xo[be*CD + t] = c0*rstd*g[e*CD + t] + bb[e*CD + t];
}

// yout = sum partials + b2 + x; gating (softmax(q@wg)) + entropy weighting
// computed inline; gated mixture -> fused, gtout.
__global__ __launch_bounds__(512) void comb_ffn2_final(
    const float* __restrict__ P, const float* __restrict__ b2,
    const float* __restrict__ xb, const float* __restrict__ q,
    const float* __restrict__ wg, const float* __restrict__ entp,
    float* __restrict__ yout, float* __restrict__ fused,
    float* __restrict__ gtout) {
  int b = blockIdx.x, t = threadIdx.x;
  int w = t >> 6, lane = t & 63;
  __shared__ float gpart[8][8];
  __shared__ float gt_s[CE];
  float ge[CE];
  {
    float qv = q[b*CD + t];
    #pragma unroll
    for (int e = 0; e < CE; e++) ge[e] = qv * wg[t*CE + e];
  }
  #pragma unroll
  for (int m = 32; m >= 1; m >>= 1) {
    #pragma unroll
    for (int e = 0; e < CE; e++) ge[e] += __shfl_xor(ge[e], m);
  }
  if (lane == 0) {
    #pragma unroll
    for (int e = 0; e < CE; e++) gpart[w][e] = ge[e];
  }
  __syncthreads();
  if (t == 0) {
    float logit[CE];
    float m = -1e30f;
    #pragma unroll
    for (int e = 0; e < CE; e++) {
      float s = 0.f;
      #pragma unroll
      for (int ww = 0; ww < 8; ww++) s += gpart[ww][e];
      logit[e] = s;
      m = fmaxf(m, s);
    }
    float ssum = 0.f, ex[CE];
    #pragma unroll
    for (int e = 0; e < CE; e++) { ex[e] = __expf(logit[e] - m); ssum += ex[e]; }
    float s2 = 0.f;
    #pragma unroll
    for (int e = 0; e < CE; e++) {
      float Hs = 0.f;
      #pragma unroll
      for (int c = 0; c < 8; c++) Hs += entp[(b*CE + e)*8 + c];
      gt_s[e] = (ex[e]/ssum) * __expf(-0.5f * Hs);
      s2 += gt_s[e];
    }
    s2 += 1e-9f;
    #pragma unroll
    for (int e = 0; e < CE; e++) gt_s[e] /= s2;
  }
  __syncthreads();
  float acc = 0.f;
  #pragma unroll
  for (int e = 0; e < CE; e++) {
    float y = b2[e*CD + t] + xb[(b*CE + e)*CD + t];
    #pragma unroll
    for (int c = 0; c < 8; c++)
      y += P[(size_t)c*65536 + (size_t)b*4096 + e*512 + t];
    yout[(b*CE + e)*CD + t] = y;
    acc += gt_s[e] * y;
  }
  fused[b*CD + t] = acc;  // ALPHA = 1.0 -> fused == mixture
  if (t < CE) gtout[b*CE + t] = gt_s[t];
}

// k4: wk_eff = Wk_slice^T @ qh (qh combined from Wq partials inline, coalesced) -> bf16 wkh;
// dt==0 block also emits sbias[b][e][h] = qh_hslice . bk_hslice.
__global__ __launch_bounds__(256) void k4_wkeff(
    const float* __restrict__ Wk, const float* __restrict__ Pq,
    const float* __restrict__ bq, const float* __restrict__ bk,
    __bf16* __restrict__ wkh, float* __restrict__ sbias) {
  int e = blockIdx.y;
  int h = blockIdx.x >> 3, dt = blockIdx.x & 7;
  int d0 = dt * 64;
  __shared__ float wks[64][65];   // [c][d]
  __shared__ float qs[64][20];    // [c][b] (pad 20: 16B-aligned rows)
  __shared__ float red[16][64];
  int t = threadIdx.x;
  for (int idx = t; idx < 64*64; idx += 256) {
    int c = idx & 63, d = idx >> 6;
    wks[c][d] = Wk[(size_t)e*CD*CD + (size_t)(d0+d)*CD + h*64 + c];
  }
  for (int idx = t; idx < 64*16; idx += 256) {
    int c = idx & 63, b = idx >> 6;   // c fastest -> coalesced partial reads
    float s = bq[e*CD + h*64 + c];
    #pragma unroll
    for (int cc = 0; cc < 8; cc++)
      s += Pq[(size_t)cc*65536 + (size_t)b*4096 + e*512 + h*64 + c];
    qs[c][b] = s;
  }
  __syncthreads();
  if (dt == 0) {
    int bb = t >> 4, ii = t & 15;
    float p = 0.f;
    #pragma unroll
    for (int j = 0; j < 4; j++)
      p += qs[ii*4 + j][bb] * bk[e*CD + h*64 + ii*4 + j];
    p += __shfl_xor(p, 1);
    p += __shfl_xor(p, 2);
    p += __shfl_xor(p, 4);
    p += __shfl_xor(p, 8);
    if (ii == 0) sbias[bb*CEH + e*8 + h] = p;
  }
  int d = t & 63, cq = t >> 6;
  float acc[16] = {};
  #pragma unroll 4
  for (int c = cq*16; c < cq*16 + 16; c++) {
    float w = wks[c][d];
    const float4* xp = reinterpret_cast<const float4*>(&qs[c][0]);
    float4 x0 = xp[0], x1 = xp[1], x2 = xp[2], x3 = xp[3];
    acc[0]  += x0.x*w; acc[1]  += x0.y*w; acc[2]  += x0.z*w; acc[3]  += x0.w*w;
    acc[4]  += x1.x*w; acc[5]  += x1.y*w; acc[6]  += x1.z*w; acc[7]  += x1.w*w;
    acc[8]  += x2.x*w; acc[9]  += x2.y*w; acc[10] += x2.z*w; acc[11] += x2.w*w;
    acc[12] += x3.x*w; acc[13] += x3.y*w; acc[14] += x3.z*w; acc[15] += x3.w*w;
  }
  if (cq == 0) { 
    #pragma unroll
    for (int b = 0; b < 16; b++) red[b][d] = acc[b]; }
  __syncthreads();
  #pragma unroll
  for (int qq = 1; qq < 4; qq++) {
    if (cq == qq) {
      #pragma unroll
      for (int b = 0; b < 16; b++) red[b][d] += acc[b];
    }
    __syncthreads();
  }
  int eh = e*8 + h;
  #pragma unroll
  for (int i = 0; i < 4; i++) {
    int b = cq*4 + i;
    wkh[((size_t)(b*CEH + eh))*CD + d0 + d] = (__bf16)red[b][d];
  }
}

// sc[b][eh][l] = (ret[b][l][:]·wk_eff[b][eh][:] + qh·bk)/8 via bf16 MFMA.
// global_load_lds double-buffered staging (BK=64), XOR-swizzled source.
__global__ __launch_bounds__(256) void k5_mfma(
    const float* __restrict__ ret, const __bf16* __restrict__ wkh,
    const float* __restrict__ sbias, float* __restrict__ sc,
    float* __restrict__ lmax, float* __restrict__ lsum) {
  int b = blockIdx.y, lt = blockIdx.x, t = threadIdx.x;
  int w = t >> 6, lane = t & 63;
  int lnlo = lane & 15, lnhi = lane >> 4;
  int lh = w & 1, ehh = w >> 1;
  int l0blk = lt*32;
  int ehbase = ehh*32;
  __shared__ __align__(16) char ldsbuf[32768];
  f32x4 acc[2];
  acc[0] = (f32x4){0.f,0.f,0.f,0.f};
  acc[1] = (f32x4){0.f,0.f,0.f,0.f};
  const float*  retb  = ret + (size_t)(b*CL + l0blk)*CD;
  const __bf16* wkhb  = wkh + (size_t)b*CEH*CD;

  int rs0 = t,        rl0 = rs0 >> 4, rg0 = ((rs0 & 15) ^ (rl0 & 15)) << 2;
  int rs1 = t + 256,  rl1 = rs1 >> 4, rg1 = ((rs1 & 15) ^ (rl1 & 15)) << 2;
  int ws0 = t,        we0 = ws0 >> 3, wg0 = ((ws0 & 7) ^ (we0 & 7)) << 3;
  int ws1 = t + 256,  we1 = ws1 >> 3, wg1 = ((ws1 & 7) ^ (we1 & 7)) << 3;

  #define K5_STAGE(bufi, kt) do {                                          \
    char* rB = ldsbuf + (bufi)*8192;                                       \
    char* wB = ldsbuf + 16384 + (bufi)*8192;                               \
    int dofs = (kt)*64;                                                    \
    GLL16(retb + (size_t)rl0*CD + dofs + rg0, rB + rs0*16);                \
    GLL16(retb + (size_t)rl1*CD + dofs + rg1, rB + rs1*16);                \
    GLL16(wkhb + (size_t)we0*CD + dofs + wg0, wB + ws0*16);                \
    GLL16(wkhb + (size_t)we1*CD + dofs + wg1, wB + ws1*16);                \
  } while (0)

  K5_STAGE(0, 0);
  __syncthreads();
  #pragma unroll
  for (int kt = 0; kt < 8; kt++) {
    int cur = kt & 1;
    if (kt < 7) K5_STAGE(cur ^ 1, kt + 1);
    const char* rB = ldsbuf + cur*8192;
    const char* wB = ldsbuf + 16384 + cur*8192;
    #pragma unroll
    for (int sub = 0; sub < 2; sub++) {
      int g0 = (sub*8 + lnhi*2 + 0) ^ lnlo;
      int g1 = (sub*8 + lnhi*2 + 1) ^ lnlo;
      float4 f0 = *reinterpret_cast<const float4*>(rB + (lh*16 + lnlo)*256 + g0*16);
      float4 f1 = *reinterpret_cast<const float4*>(rB + (lh*16 + lnlo)*256 + g1*16);
      bf16x8 bfrag;
      bfrag[0]=(__bf16)f0.x; bfrag[1]=(__bf16)f0.y; bfrag[2]=(__bf16)f0.z; bfrag[3]=(__bf16)f0.w;
      bfrag[4]=(__bf16)f1.x; bfrag[5]=(__bf16)f1.y; bfrag[6]=(__bf16)f1.z; bfrag[7]=(__bf16)f1.w;
      int ga = (sub*4 + lnhi) ^ (lnlo & 7);
      bf16x8 a0 = *reinterpret_cast<const bf16x8*>(wB + (ehbase + 0*16 + lnlo)*128 + ga*16);
      bf16x8 a1 = *reinterpret_cast<const bf16x8*>(wB + (ehbase + 1*16 + lnlo)*128 + ga*16);
      acc[0] = __builtin_amdgcn_mfma_f32_16x16x32_bf16(a0, bfrag, acc[0], 0, 0, 0);
      acc[1] = __builtin_amdgcn_mfma_f32_16x16x32_bf16(a1, bfrag, acc[1], 0, 0, 0);
    }
    __syncthreads();
  }
  #undef K5_STAGE

  int strip = lt*2 + lh;
  int l = l0blk + lh*16 + lnlo;
  #pragma unroll
  for (int et = 0; et < 2; et++) {
    #pragma unroll
    for (int i = 0; i < 4; i++) {
      int eh = ehbase + et*16 + lnhi*4 + i;
      float v = acc[et][i]*0.125f + sbias[b*CEH + eh]*0.125f;
      sc[((size_t)(b*CEH + eh))*CL + l] = v;
      float m = v;
      m = fmaxf(m, __shfl_xor(m, 1));
      m = fmaxf(m, __shfl_xor(m, 2));
      m = fmaxf(m, __shfl_xor(m, 4));
      m = fmaxf(m, __shfl_xor(m, 8));
      float s = __expf(v - m);
      s += __shfl_xor(s, 1);
      s += __shfl_xor(s, 2);
      s += __shfl_xor(s, 4);
      s += __shfl_xor(s, 8);
      if (lnlo == et*4 + i) {
        lmax[((size_t)(b*CEH + eh))*128 + strip] = m;
        lsum[((size_t)(b*CEH + eh))*128 + strip] = s;
      }
    }
  }
}

// normalize sc -> bf16 probs pb; row softmax stats reduced inline from lmax/lsum;
// entropy partials per (b,e,lchunk)
__global__ __launch_bounds__(256) void k5n(
    const float* __restrict__ sc, const float* __restrict__ lmax,
    const float* __restrict__ lsum, __bf16* __restrict__ pb,
    float* __restrict__ entp) {
  int e = blockIdx.x, b = blockIdx.y, lc = blockIdx.z, t = threadIdx.x;
  __shared__ float M_s[8], I_s[8];
  {
    int g = t >> 5, lane = t & 31;
    int eh = e*8 + g;
    const float* lm = lmax + ((size_t)(b*CEH + eh))*128;
    const float* ls = lsum + ((size_t)(b*CEH + eh))*128;
    float M = -1e30f, S = 0.f;
    #pragma unroll
    for (int j = 0; j < 4; j++) {
      float m2 = lm[lane + j*32], s2 = ls[lane + j*32];
      float Mn = fmaxf(M, m2);
      S = S*__expf(M - Mn) + s2*__expf(m2 - Mn);
      M = Mn;
    }
    #pragma unroll
    for (int mask = 16; mask >= 1; mask >>= 1) {
      float Mo = __shfl_xor(M, mask), So = __shfl_xor(S, mask);
      float Mn = fmaxf(M, Mo);
      S = S*__expf(M - Mn) + So*__expf(Mo - Mn);
      M = Mn;
    }
    if (lane == 0) { M_s[g] = M; I_s[g] = 1.f / S; }
  }
  __syncthreads();
  int l = lc*256 + t;
  float pbav = 0.f;
  #pragma unroll
  for (int h = 0; h < 8; h++) {
    size_t ix = ((size_t)(b*CEH + e*8 + h))*CL + l;
    float p = __expf(sc[ix] - M_s[h]) * I_s[h];
    pb[ix] = (__bf16)p;
    pbav += p;
  }
  pbav = fmaxf(pbav*0.125f, 1e-12f);
  float ent = -pbav * __logf(pbav);
  __shared__ float red[256];
  red[t] = ent; __syncthreads();
  for (int s = 128; s > 0; s >>= 1) { if (t < s) red[t] += red[t+s]; __syncthreads(); }
  if (t == 0) entp[(b*CE + e)*8 + lc] = red[0];
}

// reff partial[lc][b][eh][d] = sum_{l in 512-chunk} P[b][eh][l] * ret[b][l][d] via bf16 MFMA.
// 8 d-tiles x 4 L-chunks per b; ping-pong LDS + register prefetch, 16 K-steps.
__global__ __launch_bounds__(256) void k6_mfma(
    const __bf16* __restrict__ pb, const float* __restrict__ ret,
    float* __restrict__ part) {
  int b = blockIdx.y;
  int dt = blockIdx.x & 7, lc = blockIdx.x >> 3;
  int d0 = dt*64, l0 = lc*512;
  int t = threadIdx.x, w = t >> 6, lane = t & 63;
  int lnlo = lane & 15, lnhi = lane >> 4;
  __shared__ __bf16 Bs[2][64][40];   // [buf][d][l] transposed ret tile
  f32x4 acc[4];
  #pragma unroll
  for (int et = 0; et < 4; et++) acc[et] = (f32x4){0.f,0.f,0.f,0.f};
  const __bf16* pbb = pb + ((size_t)(b*CEH) + lnlo)*CL + l0 + lnhi*8;
  int srow = t & 31, scol = (t >> 5)*8;
  const float* retb = ret + ((size_t)(b*CL) + l0 + srow)*CD + d0 + scol;
  float4 v0 = *reinterpret_cast<const float4*>(retb);
  float4 v1 = *reinterpret_cast<const float4*>(retb + 4);
  bf16x8 ap0 = *reinterpret_cast<const bf16x8*>(pbb);
  bf16x8 ap1 = *reinterpret_cast<const bf16x8*>(pbb + (size_t)16*CL);
  bf16x8 ap2 = *reinterpret_cast<const bf16x8*>(pbb + (size_t)32*CL);
  bf16x8 ap3 = *reinterpret_cast<const bf16x8*>(pbb + (size_t)48*CL);
  #pragma unroll
  for (int kt = 0; kt < 16; kt++) {
    int cur = kt & 1;
    Bs[cur][scol+0][srow] = (__bf16)v0.x; Bs[cur][scol+1][srow] = (__bf16)v0.y;
    Bs[cur][scol+2][srow] = (__bf16)v0.z; Bs[cur][scol+3][srow] = (__bf16)v0.w;
    Bs[cur][scol+4][srow] = (__bf16)v1.x; Bs[cur][scol+5][srow] = (__bf16)v1.y;
    Bs[cur][scol+6][srow] = (__bf16)v1.z; Bs[cur][scol+7][srow] = (__bf16)v1.w;
    bf16x8 an0, an1, an2, an3;
    if (kt < 15) {
      v0 = *reinterpret_cast<const float4*>(retb + (size_t)(kt+1)*32*CD);
      v1 = *reinterpret_cast<const float4*>(retb + (size_t)(kt+1)*32*CD + 4);
      an0 = *reinterpret_cast<const bf16x8*>(pbb + (kt+1)*32);
      an1 = *reinterpret_cast<const bf16x8*>(pbb + (size_t)16*CL + (kt+1)*32);
      an2 = *reinterpret_cast<const bf16x8*>(pbb + (size_t)32*CL + (kt+1)*32);
      an3 = *reinterpret_cast<const bf16x8*>(pbb + (size_t)48*CL + (kt+1)*32);
    }
    __syncthreads();
    bf16x8 bfrag = *reinterpret_cast<const bf16x8*>(&Bs[cur][w*16 + lnlo][lnhi*8]);
    acc[0] = __builtin_amdgcn_mfma_f32_16x16x32_bf16(ap0, bfrag, acc[0], 0, 0, 0);
    acc[1] = __builtin_amdgcn_mfma_f32_16x16x32_bf16(ap1, bfrag, acc[1], 0, 0, 0);
    acc[2] = __builtin_amdgcn_mfma_f32_16x16x32_bf16(ap2, bfrag, acc[2], 0, 0, 0);
    acc[3] = __builtin_amdgcn_mfma_f32_16x16x32_bf16(ap3, bfrag, acc[3], 0, 0, 0);
    if (kt < 15) { ap0 = an0; ap1 = an1; ap2 = an2; ap3 = an3; }
    __syncthreads();
  }
  float* dst = part + (size_t)lc*(CB*CEH*CD);
  int d = d0 + w*16 + lnlo;
  #pragma unroll
  for (int et = 0; et < 4; et++) {
    #pragma unroll
    for (int i = 0; i < 4; i++) {
      int eh = et*16 + lnhi*4 + i;
      dst[((size_t)(b*CEH + eh))*CD + d] = acc[et][i];
    }
  }
}

extern "C" void kernel_launch(void* const* d_in, const int* in_sizes, int n_in,
                              void* d_out, int out_size, void* d_ws, size_t ws_size,
                              hipStream_t stream) {
  const float* q    = (const float*)d_in[0];
  const float* ret  = (const float*)d_in[1];
  const float* wg   = (const float*)d_in[2];
  const float* lnqg = (const float*)d_in[3];
  const float* lnqb = (const float*)d_in[4];
  const float* Wq   = (const float*)d_in[5];
  const float* bq   = (const float*)d_in[6];
  const float* Wk   = (const float*)d_in[7];
  const float* bk   = (const float*)d_in[8];
  const float* Wv   = (const float*)d_in[9];
  const float* bv   = (const float*)d_in[10];
  const float* Wo   = (const float*)d_in[11];
  const float* bo   = (const float*)d_in[12];
  const float* lnog = (const float*)d_in[13];
  const float* lnob = (const float*)d_in[14];
  const float* W1   = (const float*)d_in[15];
  const float* b1   = (const float*)d_in[16];
  const float* W2   = (const float*)d_in[17];
  const float* b2   = (const float*)d_in[18];

  float* ws = (float*)d_ws;
  float* fused = (float*)d_out;
  float* yout  = fused + CB*CD;
  float* gtout = yout + CB*CE*CD;

  float* sbias = ws + WS_SBIAS;
  __bf16* wkh  = (__bf16*)(ws + WS_WK);
  float* sc    = ws + WS_SC;
  float* part0 = ws + WS_PART;
  float* part1 = ws + WS_PART1;
  float* entp  = ws + WS_ENT;
  float* xb    = ws + WS_X;
  float* xo    = ws + WS_XO;
  float* rpart = ws + WS_RP;
  __bf16* pb16 = (__bf16*)(ws + WS_PB16);
  float* lmax  = rpart;                      // dead before k6_mfma writes rpart
  float* lsum  = rpart + CB*CEH*128;

  // qh partials = LN(q)*g+b @ Wq : LN fused into staging
  gstream_wq<<<dim3(64, CE), 256, 0, stream>>>(q, lnqg, lnqb, Wq, part0);
  // wk_eff (bf16) from Wk and combined qh; dt==0 blocks emit sbias
  k4_wkeff<<<dim3(64, CE), 256, 0, stream>>>(Wk, part0, bq, bk, wkh, sbias);
  k5_mfma<<<dim3(64, CB), 256, 0, stream>>>(ret, wkh, sbias, sc, lmax, lsum);
  k5n<<<dim3(CE, CB, 8), 256, 0, stream>>>(sc, lmax, lsum, pb16, entp);
  k6_mfma<<<dim3(32, CB), 256, 0, stream>>>(pb16, ret, rpart);
  // attn partials (over d-chunks) from reff(=sum 4 rpart) @ Wv
  gstream_v<<<dim3(8, CEH), 256, 0, stream>>>(rpart, Wv, part1);
  // x-partials: (attn = sum part1 + bv) @ Wo
  gstream_wo<<<dim3(64, CE), 256, 0, stream>>>(part1, bv, Wo, part0);
  comb_o_lno<<<CB*CE, 512, 0, stream>>>(part0, bo, q, lnog, lnob, xb, xo);
  // FFN1 partials = xo @ W1 : K=512 (4 chunks of 128), N=2048 (32 tiles)
  gstream<128><<<dim3(128, CE), 256, 0, stream>>>(xo, CE*CD, CD, W1, (size_t)CD*CF, CF,
                                                  part0, 32, 262144, CE*CF, CF);
  // y-partials = gelu(FFN1) @ W2 : staging applies bias+GELU (coalesced); -> rpart
  gstream_w2<<<dim3(64, CE), 256, 0, stream>>>(part0, b1, W2, rpart);
  comb_ffn2_final<<<CB, 512, 0, stream>>>(rpart, b2, xb, q, wg, entp, yout, fused, gtout);
}

// Round 16
// 118.838 us; speedup vs baseline: 1.0549x; 1.0018x over previous
//
#include <hip/hip_runtime.h>
#include <math.h>

#define CB 16
#define CL 2048
#define CD 512
#define CE 8
#define CH 8
#define CEH 64
#define CF 2048

typedef __bf16 bf16x8 __attribute__((ext_vector_type(8)));
typedef float f32x4 __attribute__((ext_vector_type(4)));

#define GLL16(srcp, dstp) __builtin_amdgcn_global_load_lds( \
    (const __attribute__((address_space(1))) unsigned int*)(srcp), \
    (__attribute__((address_space(3))) unsigned int*)(dstp), 16, 0, 0)

// ws layout (float offsets)
#define WS_GATES 0
#define WS_XN    (WS_GATES + CB*CE)
#define WS_QN    (WS_XN + CB*CD)
#define WS_QH    (WS_QN + CB*CE*CD)
#define WS_SBIAS (WS_QH + CB*CE*CD)
#define WS_WK    (WS_SBIAS + CB*CE*CH)          /* bf16 wkh [b][eh][d] */
#define WS_SC    (WS_WK + CB*CEH*CD)            /* bf16 sc [b][eh][l]; partials alias (liveness disjoint) */
#define WS_PART  WS_SC
#define WS_PART1 (WS_PART + 524288)
#define WS_ENT   (WS_SC + CB*CL*CEH)            /* [b][e][8] chunk partials */
#define WS_ATTN  (WS_ENT + CB*CE*8)
#define WS_X     (WS_ATTN + CB*CE*CD)
#define WS_XO    (WS_X + CB*CE*CD)
#define WS_HB    (WS_XO + CB*CE*CD)
#define WS_RP    (WS_HB + CB*CE*CF)             /* 4 * CB*CEH*CD fp32 partials; lmax/lsum alias head; W2 partials reuse */
#define WS_PB16  (WS_RP + 8*CB*CEH*CD)          /* bf16 probs [b][eh][l] */

// Wq stream with fused query-LayerNorm staging.
__global__ __launch_bounds__(256) void gstream_wq(
    const float* __restrict__ q, const float* __restrict__ g,
    const float* __restrict__ bln, const float* __restrict__ W,
    float* __restrict__ P) {
  int e = blockIdx.y;
  int nt = blockIdx.x % 8, kc = blockIdx.x / 8;
  int n0 = nt * 64, k0 = kc * 64;
  __shared__ float xs[64][20];
  __shared__ float red[16][64];
  __shared__ float muS[16], rsS[16];
  int t = threadIdx.x;
  {
    int b = t >> 4, j = t & 15;
    float s1 = 0.f, s2 = 0.f;
    const float* qb = q + b*CD + j*32;
    #pragma unroll
    for (int i = 0; i < 32; i++) { float v = qb[i]; s1 += v; s2 += v*v; }
    #pragma unroll
    for (int m = 1; m <= 8; m <<= 1) { s1 += __shfl_xor(s1, m); s2 += __shfl_xor(s2, m); }
    if (j == 0) {
      float mu = s1 * (1.0f/CD);
      float var = s2 * (1.0f/CD) - mu*mu;
      muS[b] = mu;
      rsS[b] = rsqrtf(var + 1e-5f);
    }
  }
  __syncthreads();
  for (int idx = t; idx < 64*16; idx += 256) {
    int k = idx & 63, b = idx >> 6;   // k fastest -> coalesced
    xs[k][b] = (q[b*CD + k0 + k] - muS[b]) * rsS[b] * g[e*CD + k0 + k] + bln[e*CD + k0 + k];
  }
  __syncthreads();
  int n = t & 63, kq = t >> 6;
  float acc[16] = {};
  const float* Wp = W + (size_t)e*CD*CD + (size_t)k0*CD + n0 + n;
  #pragma unroll 4
  for (int k = kq*16; k < kq*16 + 16; k++) {
    float w = Wp[(size_t)k * CD];
    const float4* xp = reinterpret_cast<const float4*>(&xs[k][0]);
    float4 x0 = xp[0], x1 = xp[1], x2 = xp[2], x3 = xp[3];
    acc[0]  += x0.x*w; acc[1]  += x0.y*w; acc[2]  += x0.z*w; acc[3]  += x0.w*w;
    acc[4]  += x1.x*w; acc[5]  += x1.y*w; acc[6]  += x1.z*w; acc[7]  += x1.w*w;
    acc[8]  += x2.x*w; acc[9]  += x2.y*w; acc[10] += x2.z*w; acc[11] += x2.w*w;
    acc[12] += x3.x*w; acc[13] += x3.y*w; acc[14] += x3.z*w; acc[15] += x3.w*w;
  }
  if (kq == 0) {
    #pragma unroll
    for (int b = 0; b < 16; b++) red[b][n] = acc[b];
  }
  __syncthreads();
  #pragma unroll
  for (int qq = 1; qq < 4; qq++) {
    if (kq == qq) {
      #pragma unroll
      for (int b = 0; b < 16; b++) red[b][n] += acc[b];
    }
    __syncthreads();
  }
  #pragma unroll
  for (int i = 0; i < 4; i++) {
    int b = kq*4 + i;
    P[(size_t)kc*65536 + (size_t)b*4096 + (size_t)e*512 + n0 + n] = red[b][n];
  }
}

// W1 stream with fused output-LayerNorm staging: recompute per-(b,e) LN stats
// from xb (L2-hot), stage xo = LN(xb)*g+bb on the fly, stream W1 column block.
__global__ __launch_bounds__(256) void gstream_w1(
    const float* __restrict__ xb, const float* __restrict__ g,
    const float* __restrict__ bb, const float* __restrict__ W1,
    float* __restrict__ P) {
  int e = blockIdx.y;
  int nt = blockIdx.x % 32, kc = blockIdx.x / 32;
  int n0 = nt * 64, k0 = kc * 128;
  __shared__ float xs[128][20];
  __shared__ float red[16][64];
  __shared__ float muS[16], rsS[16];
  int t = threadIdx.x;
  {
    int b = t >> 4, j = t & 15;
    float s1 = 0.f, s2 = 0.f;
    const float* xr = xb + (size_t)(b*CE + e)*CD + j*32;
    #pragma unroll
    for (int i = 0; i < 32; i++) { float v = xr[i]; s1 += v; s2 += v*v; }
    #pragma unroll
    for (int m = 1; m <= 8; m <<= 1) { s1 += __shfl_xor(s1, m); s2 += __shfl_xor(s2, m); }
    if (j == 0) {
      float mu = s1 * (1.0f/CD);
      float var = s2 * (1.0f/CD) - mu*mu;
      muS[b] = mu;
      rsS[b] = rsqrtf(var + 1e-5f);
    }
  }
  __syncthreads();
  for (int idx = t; idx < 128*16; idx += 256) {
    int k = idx & 127, b = idx >> 7;   // k fastest -> coalesced
    xs[k][b] = (xb[(size_t)(b*CE + e)*CD + k0 + k] - muS[b]) * rsS[b] * g[e*CD + k0 + k]
               + bb[e*CD + k0 + k];
  }
  __syncthreads();
  int n = t & 63, kq = t >> 6;
  float acc[16] = {};
  const float* Wp = W1 + (size_t)e*CD*CF + (size_t)k0*CF + n0 + n;
  #pragma unroll 4
  for (int k = kq*32; k < kq*32 + 32; k++) {
    float w = Wp[(size_t)k * CF];
    const float4* xp = reinterpret_cast<const float4*>(&xs[k][0]);
    float4 x0 = xp[0], x1 = xp[1], x2 = xp[2], x3 = xp[3];
    acc[0]  += x0.x*w; acc[1]  += x0.y*w; acc[2]  += x0.z*w; acc[3]  += x0.w*w;
    acc[4]  += x1.x*w; acc[5]  += x1.y*w; acc[6]  += x1.z*w; acc[7]  += x1.w*w;
    acc[8]  += x2.x*w; acc[9]  += x2.y*w; acc[10] += x2.z*w; acc[11] += x2.w*w;
    acc[12] += x3.x*w; acc[13] += x3.y*w; acc[14] += x3.z*w; acc[15] += x3.w*w;
  }
  if (kq == 0) {
    #pragma unroll
    for (int b = 0; b < 16; b++) red[b][n] = acc[b];
  }
  __syncthreads();
  #pragma unroll
  for (int qq = 1; qq < 4; qq++) {
    if (kq == qq) {
      #pragma unroll
      for (int b = 0; b < 16; b++) red[b][n] += acc[b];
    }
    __syncthreads();
  }
  #pragma unroll
  for (int i = 0; i < 4; i++) {
    int b = kq*4 + i;
    P[(size_t)kc*262144 + (size_t)b*16384 + (size_t)e*2048 + n0 + n] = red[b][n];
  }
}

// Wv variant: sums the 4 k6 partials during staging, then streams Wv column block.
__global__ __launch_bounds__(256) void gstream_v(
    const float* __restrict__ rp, const float* __restrict__ Wv,
    float* __restrict__ P) {
  int eh = blockIdx.y, kc = blockIdx.x;
  int e = eh >> 3, h = eh & 7;
  int k0 = kc * 64;
  __shared__ float xs[64][20];
  __shared__ float red[16][64];
  int t = threadIdx.x;
  for (int idx = t; idx < 64 * 16; idx += 256) {
    int k = idx & 63, b = idx >> 6;   // k fastest -> coalesced
    float s = 0.f;
    #pragma unroll
    for (int c = 0; c < 4; c++)
      s += rp[(size_t)c*(CB*CEH*CD) + ((size_t)(b*CEH + eh))*CD + k0 + k];
    xs[k][b] = s;
  }
  __syncthreads();
  int n = t & 63, kq = t >> 6;
  float acc[16] = {};
  const float* Wp = Wv + (size_t)e*CD*CD + (size_t)k0*CD + h*64 + n;
  #pragma unroll 4
  for (int k = kq*16; k < kq*16 + 16; k++) {
    float w = Wp[(size_t)k * CD];
    const float4* xp = reinterpret_cast<const float4*>(&xs[k][0]);
    float4 x0 = xp[0], x1 = xp[1], x2 = xp[2], x3 = xp[3];
    acc[0]  += x0.x*w; acc[1]  += x0.y*w; acc[2]  += x0.z*w; acc[3]  += x0.w*w;
    acc[4]  += x1.x*w; acc[5]  += x1.y*w; acc[6]  += x1.z*w; acc[7]  += x1.w*w;
    acc[8]  += x2.x*w; acc[9]  += x2.y*w; acc[10] += x2.z*w; acc[11] += x2.w*w;
    acc[12] += x3.x*w; acc[13] += x3.y*w; acc[14] += x3.z*w; acc[15] += x3.w*w;
  }
  if (kq == 0) { 
    #pragma unroll
    for (int b = 0; b < 16; b++) red[b][n] = acc[b]; }
  __syncthreads();
  #pragma unroll
  for (int qq = 1; qq < 4; qq++) {
    if (kq == qq) {
      #pragma unroll
      for (int b = 0; b < 16; b++) red[b][n] += acc[b];
    }
    __syncthreads();
  }
  #pragma unroll
  for (int i = 0; i < 4; i++) {
    int b = kq*4 + i;
    P[(size_t)kc*65536 + (size_t)b*4096 + (size_t)eh*64 + n] = red[b][n];
  }
}

// Wo stream: staging computes attn = sum(Pv partials) + bv, then streams Wo.
__global__ __launch_bounds__(256) void gstream_wo(
    const float* __restrict__ Pv, const float* __restrict__ bv,
    const float* __restrict__ Wo, float* __restrict__ P) {
  int e = blockIdx.y;
  int nt = blockIdx.x % 8, kc = blockIdx.x / 8;
  int n0 = nt * 64, k0 = kc * 64;
  __shared__ float xs[64][20];
  __shared__ float red[16][64];
  int t = threadIdx.x;
  for (int idx = t; idx < 64 * 16; idx += 256) {
    int k = idx & 63, b = idx >> 6;   // k fastest -> coalesced
    float s = bv[e*CD + k0 + k];
    #pragma unroll
    for (int c = 0; c < 8; c++)
      s += Pv[(size_t)c*65536 + (size_t)b*4096 + e*512 + k0 + k];
    xs[k][b] = s;
  }
  __syncthreads();
  int n = t & 63, kq = t >> 6;
  float acc[16] = {};
  const float* Wp = Wo + (size_t)e*CD*CD + (size_t)k0*CD + n0 + n;
  #pragma unroll 4
  for (int k = kq*16; k < kq*16 + 16; k++) {
    float w = Wp[(size_t)k * CD];
    const float4* xp = reinterpret_cast<const float4*>(&xs[k][0]);
    float4 x0 = xp[0], x1 = xp[1], x2 = xp[2], x3 = xp[3];
    acc[0]  += x0.x*w; acc[1]  += x0.y*w; acc[2]  += x0.z*w; acc[3]  += x0.w*w;
    acc[4]  += x1.x*w; acc[5]  += x1.y*w; acc[6]  += x1.z*w; acc[7]  += x1.w*w;
    acc[8]  += x2.x*w; acc[9]  += x2.y*w; acc[10] += x2.z*w; acc[11] += x2.w*w;
    acc[12] += x3.x*w; acc[13] += x3.y*w; acc[14] += x3.z*w; acc[15] += x3.w*w;
  }
  if (kq == 0) {
    #pragma unroll
    for (int b = 0; b < 16; b++) red[b][n] = acc[b]; }
  __syncthreads();
  #pragma unroll
  for (int qq = 1; qq < 4; qq++) {
    if (kq == qq) {
      #pragma unroll
      for (int b = 0; b < 16; b++) red[b][n] += acc[b];
    }
    __syncthreads();
  }
  #pragma unroll
  for (int i = 0; i < 4; i++) {
    int b = kq*4 + i;
    P[(size_t)kc*65536 + (size_t)b*4096 + (size_t)e*512 + n0 + n] = red[b][n];
  }
}

// W2 stream: staging computes h = gelu(sum(4 FFN1 partials) + b1), streams W2.
__global__ __launch_bounds__(256) void gstream_w2(
    const float* __restrict__ P1, const float* __restrict__ b1,
    const float* __restrict__ W2, float* __restrict__ Pout) {
  int e = blockIdx.y;
  int nt = blockIdx.x % 8, kc = blockIdx.x / 8;
  int n0 = nt * 64, k0 = kc * 256;
  __shared__ float xs[256][20];
  __shared__ float red[16][64];
  int t = threadIdx.x;
  for (int idx = t; idx < 256 * 16; idx += 256) {
    int k = idx & 255, b = idx >> 8;   // k fastest -> coalesced
    float v = b1[e*CF + k0 + k];
    #pragma unroll
    for (int c = 0; c < 4; c++)
      v += P1[(size_t)c*262144 + (size_t)b*16384 + e*2048 + k0 + k];
    xs[k][b] = 0.5f*v*(1.f + erff(v*0.70710678118f));
  }
  __syncthreads();
  int n = t & 63, kq = t >> 6;
  float acc[16] = {};
  const float* Wp = W2 + (size_t)e*CF*CD + (size_t)k0*CD + n0 + n;
  #pragma unroll 4
  for (int k = kq*64; k < kq*64 + 64; k++) {
    float w = Wp[(size_t)k * CD];
    const float4* xp = reinterpret_cast<const float4*>(&xs[k][0]);
    float4 x0 = xp[0], x1 = xp[1], x2 = xp[2], x3 = xp[3];
    acc[0]  += x0.x*w; acc[1]  += x0.y*w; acc[2]  += x0.z*w; acc[3]  += x0.w*w;
    acc[4]  += x1.x*w; acc[5]  += x1.y*w; acc[6]  += x1.z*w; acc[7]  += x1.w*w;
    acc[8]  += x2.x*w; acc[9]  += x2.y*w; acc[10] += x2.z*w; acc[11] += x2.w*w;
    acc[12] += x3.x*w; acc[13] += x3.y*w; acc[14] += x3.z*w; acc[15] += x3.w*w;
  }
  if (kq == 0) {
    #pragma unroll
    for (int b = 0; b < 16; b++) red[b][n] = acc[b]; }
  __syncthreads();
  #pragma unroll
  for (int qq = 1; qq < 4; qq++) {
    if (kq == qq) {
      #pragma unroll
      for (int b = 0; b < 16; b++) red[b][n] += acc[b];
    }
    __syncthreads();
  }
  #pragma unroll
  for (int i = 0; i < 4; i++) {
    int b = kq*4 + i;
    Pout[(size_t)kc*65536 + (size_t)b*4096 + (size_t)e*512 + n0 + n] = red[b][n];
  }
}

// x = q + sum partials + bo (residual only; LN moved into gstream_w1 staging)
__global__ __launch_bounds__(512) void comb_o(
    const float* __restrict__ P, const float* __restrict__ bo,
    const float* __restrict__ q, float* __restrict__ xb) {
  int be = blockIdx.x, b = be >> 3, e = be & 7, t = threadIdx.x;
  float v = q[b*CD + t] + bo[e*CD + t];
  #pragma unroll
  for (int c = 0; c < 8; c++)
    v += P[(size_t)c*65536 + (size_t)b*4096 + e*512 + t];
  xb[be*CD + t] = v;
}

// yout = sum partials + b2 + x; gating (softmax(q@wg)) + entropy weighting
// computed inline; gated mixture -> fused, gtout.
__global__ __launch_bounds__(512) void comb_ffn2_final(
    const float* __restrict__ P, const float* __restrict__ b2,
    const float* __restrict__ xb, const float* __restrict__ q,
    const float* __restrict__ wg, const float* __restrict__ entp,
    float* __restrict__ yout, float* __restrict__ fused,
    float* __restrict__ gtout) {
  int b = blockIdx.x, t = threadIdx.x;
  int w = t >> 6, lane = t & 63;
  __shared__ float gpart[8][8];
  __shared__ float gt_s[CE];
  float ge[CE];
  {
    float qv = q[b*CD + t];
    #pragma unroll
    for (int e = 0; e < CE; e++) ge[e] = qv * wg[t*CE + e];
  }
  #pragma unroll
  for (int m = 32; m >= 1; m >>= 1) {
    #pragma unroll
    for (int e = 0; e < CE; e++) ge[e] += __shfl_xor(ge[e], m);
  }
  if (lane == 0) {
    #pragma unroll
    for (int e = 0; e < CE; e++) gpart[w][e] = ge[e];
  }
  __syncthreads();
  if (t == 0) {
    float logit[CE];
    float m = -1e30f;
    #pragma unroll
    for (int e = 0; e < CE; e++) {
      float s = 0.f;
      #pragma unroll
      for (int ww = 0; ww < 8; ww++) s += gpart[ww][e];
      logit[e] = s;
      m = fmaxf(m, s);
    }
    float ssum = 0.f, ex[CE];
    #pragma unroll
    for (int e = 0; e < CE; e++) { ex[e] = __expf(logit[e] - m); ssum += ex[e]; }
    float s2 = 0.f;
    #pragma unroll
    for (int e = 0; e < CE; e++) {
      float Hs = 0.f;
      #pragma unroll
      for (int c = 0; c < 8; c++) Hs += entp[(b*CE + e)*8 + c];
      gt_s[e] = (ex[e]/ssum) * __expf(-0.5f * Hs);
      s2 += gt_s[e];
    }
    s2 += 1e-9f;
    #pragma unroll
    for (int e = 0; e < CE; e++) gt_s[e] /= s2;
  }
  __syncthreads();
  float acc = 0.f;
  #pragma unroll
  for (int e = 0; e < CE; e++) {
    float y = b2[e*CD + t] + xb[(b*CE + e)*CD + t];
    #pragma unroll
    for (int c = 0; c < 8; c++)
      y += P[(size_t)c*65536 + (size_t)b*4096 + e*512 + t];
    yout[(b*CE + e)*CD + t] = y;
    acc += gt_s[e] * y;
  }
  fused[b*CD + t] = acc;  // ALPHA = 1.0 -> fused == mixture
  if (t < CE) gtout[b*CE + t] = gt_s[t];
}

// k4: wk_eff = Wk_slice^T @ qh (qh combined from Wq partials inline, coalesced) -> bf16 wkh;
// dt==0 block also emits sbias[b][e][h] = qh_hslice . bk_hslice.
__global__ __launch_bounds__(256) void k4_wkeff(
    const float* __restrict__ Wk, const float* __restrict__ Pq,
    const float* __restrict__ bq, const float* __restrict__ bk,
    __bf16* __restrict__ wkh, float* __restrict__ sbias) {
  int e = blockIdx.y;
  int h = blockIdx.x >> 3, dt = blockIdx.x & 7;
  int d0 = dt * 64;
  __shared__ float wks[64][65];   // [c][d]
  __shared__ float qs[64][20];    // [c][b] (pad 20: 16B-aligned rows)
  __shared__ float red[16][64];
  int t = threadIdx.x;
  for (int idx = t; idx < 64*64; idx += 256) {
    int c = idx & 63, d = idx >> 6;
    wks[c][d] = Wk[(size_t)e*CD*CD + (size_t)(d0+d)*CD + h*64 + c];
  }
  for (int idx = t; idx < 64*16; idx += 256) {
    int c = idx & 63, b = idx >> 6;   // c fastest -> coalesced partial reads
    float s = bq[e*CD + h*64 + c];
    #pragma unroll
    for (int cc = 0; cc < 8; cc++)
      s += Pq[(size_t)cc*65536 + (size_t)b*4096 + e*512 + h*64 + c];
    qs[c][b] = s;
  }
  __syncthreads();
  if (dt == 0) {
    int bb = t >> 4, ii = t & 15;
    float p = 0.f;
    #pragma unroll
    for (int j = 0; j < 4; j++)
      p += qs[ii*4 + j][bb] * bk[e*CD + h*64 + ii*4 + j];
    p += __shfl_xor(p, 1);
    p += __shfl_xor(p, 2);
    p += __shfl_xor(p, 4);
    p += __shfl_xor(p, 8);
    if (ii == 0) sbias[bb*CEH + e*8 + h] = p;
  }
  int d = t & 63, cq = t >> 6;
  float acc[16] = {};
  #pragma unroll 4
  for (int c = cq*16; c < cq*16 + 16; c++) {
    float w = wks[c][d];
    const float4* xp = reinterpret_cast<const float4*>(&qs[c][0]);
    float4 x0 = xp[0], x1 = xp[1], x2 = xp[2], x3 = xp[3];
    acc[0]  += x0.x*w; acc[1]  += x0.y*w; acc[2]  += x0.z*w; acc[3]  += x0.w*w;
    acc[4]  += x1.x*w; acc[5]  += x1.y*w; acc[6]  += x1.z*w; acc[7]  += x1.w*w;
    acc[8]  += x2.x*w; acc[9]  += x2.y*w; acc[10] += x2.z*w; acc[11] += x2.w*w;
    acc[12] += x3.x*w; acc[13] += x3.y*w; acc[14] += x3.z*w; acc[15] += x3.w*w;
  }
  if (cq == 0) { 
    #pragma unroll
    for (int b = 0; b < 16; b++) red[b][d] = acc[b]; }
  __syncthreads();
  #pragma unroll
  for (int qq = 1; qq < 4; qq++) {
    if (cq == qq) {
      #pragma unroll
      for (int b = 0; b < 16; b++) red[b][d] += acc[b];
    }
    __syncthreads();
  }
  int eh = e*8 + h;
  #pragma unroll
  for (int i = 0; i < 4; i++) {
    int b = cq*4 + i;
    wkh[((size_t)(b*CEH + eh))*CD + d0 + d] = (__bf16)red[b][d];
  }
}

// sc[b][eh][l] = bf16((ret·wk_eff + qh·bk)/8) via bf16 MFMA; strip stats computed
// from the bf16-quantized value so k5n's normalization is exactly consistent.
__global__ __launch_bounds__(256) void k5_mfma(
    const float* __restrict__ ret, const __bf16* __restrict__ wkh,
    const float* __restrict__ sbias, __bf16* __restrict__ sc,
    float* __restrict__ lmax, float* __restrict__ lsum) {
  int b = blockIdx.y, lt = blockIdx.x, t = threadIdx.x;
  int w = t >> 6, lane = t & 63;
  int lnlo = lane & 15, lnhi = lane >> 4;
  int lh = w & 1, ehh = w >> 1;
  int l0blk = lt*32;
  int ehbase = ehh*32;
  __shared__ __align__(16) char ldsbuf[32768];
  f32x4 acc[2];
  acc[0] = (f32x4){0.f,0.f,0.f,0.f};
  acc[1] = (f32x4){0.f,0.f,0.f,0.f};
  const float*  retb  = ret + (size_t)(b*CL + l0blk)*CD;
  const __bf16* wkhb  = wkh + (size_t)b*CEH*CD;

  int rs0 = t,        rl0 = rs0 >> 4, rg0 = ((rs0 & 15) ^ (rl0 & 15)) << 2;
  int rs1 = t + 256,  rl1 = rs1 >> 4, rg1 = ((rs1 & 15) ^ (rl1 & 15)) << 2;
  int ws0 = t,        we0 = ws0 >> 3, wg0 = ((ws0 & 7) ^ (we0 & 7)) << 3;
  int ws1 = t + 256,  we1 = ws1 >> 3, wg1 = ((ws1 & 7) ^ (we1 & 7)) << 3;

  #define K5_STAGE(bufi, kt) do {                                          \
    char* rB = ldsbuf + (bufi)*8192;                                       \
    char* wB = ldsbuf + 16384 + (bufi)*8192;                               \
    int dofs = (kt)*64;                                                    \
    GLL16(retb + (size_t)rl0*CD + dofs + rg0, rB + rs0*16);                \
    GLL16(retb + (size_t)rl1*CD + dofs + rg1, rB + rs1*16);                \
    GLL16(wkhb + (size_t)we0*CD + dofs + wg0, wB + ws0*16);                \
    GLL16(wkhb + (size_t)we1*CD + dofs + wg1, wB + ws1*16);                \
  } while (0)

  K5_STAGE(0, 0);
  __syncthreads();
  #pragma unroll
  for (int kt = 0; kt < 8; kt++) {
    int cur = kt & 1;
    if (kt < 7) K5_STAGE(cur ^ 1, kt + 1);
    const char* rB = ldsbuf + cur*8192;
    const char* wB = ldsbuf + 16384 + cur*8192;
    #pragma unroll
    for (int sub = 0; sub < 2; sub++) {
      int g0 = (sub*8 + lnhi*2 + 0) ^ lnlo;
      int g1 = (sub*8 + lnhi*2 + 1) ^ lnlo;
      float4 f0 = *reinterpret_cast<const float4*>(rB + (lh*16 + lnlo)*256 + g0*16);
      float4 f1 = *reinterpret_cast<const float4*>(rB + (lh*16 + lnlo)*256 + g1*16);
      bf16x8 bfrag;
      bfrag[0]=(__bf16)f0.x; bfrag[1]=(__bf16)f0.y; bfrag[2]=(__bf16)f0.z; bfrag[3]=(__bf16)f0.w;
      bfrag[4]=(__bf16)f1.x; bfrag[5]=(__bf16)f1.y; bfrag[6]=(__bf16)f1.z; bfrag[7]=(__bf16)f1.w;
      int ga = (sub*4 + lnhi) ^ (lnlo & 7);
      bf16x8 a0 = *reinterpret_cast<const bf16x8*>(wB + (ehbase + 0*16 + lnlo)*128 + ga*16);
      bf16x8 a1 = *reinterpret_cast<const bf16x8*>(wB + (ehbase + 1*16 + lnlo)*128 + ga*16);
      acc[0] = __builtin_amdgcn_mfma_f32_16x16x32_bf16(a0, bfrag, acc[0], 0, 0, 0);
      acc[1] = __builtin_amdgcn_mfma_f32_16x16x32_bf16(a1, bfrag, acc[1], 0, 0, 0);
    }
    __syncthreads();
  }
  #undef K5_STAGE

  int strip = lt*2 + lh;
  int l = l0blk + lh*16 + lnlo;
  #pragma unroll
  for (int et = 0; et < 2; et++) {
    #pragma unroll
    for (int i = 0; i < 4; i++) {
      int eh = ehbase + et*16 + lnhi*4 + i;
      float v = acc[et][i]*0.125f + sbias[b*CEH + eh]*0.125f;
      __bf16 vb = (__bf16)v;
      sc[((size_t)(b*CEH + eh))*CL + l] = vb;
      float vq = (float)vb;
      float m = vq;
      m = fmaxf(m, __shfl_xor(m, 1));
      m = fmaxf(m, __shfl_xor(m, 2));
      m = fmaxf(m, __shfl_xor(m, 4));
      m = fmaxf(m, __shfl_xor(m, 8));
      float s = __expf(vq - m);
      s += __shfl_xor(s, 1);
      s += __shfl_xor(s, 2);
      s += __shfl_xor(s, 4);
      s += __shfl_xor(s, 8);
      if (lnlo == et*4 + i) {
        lmax[((size_t)(b*CEH + eh))*128 + strip] = m;
        lsum[((size_t)(b*CEH + eh))*128 + strip] = s;
      }
    }
  }
}

// normalize bf16 sc -> bf16 probs pb; row softmax stats reduced inline from lmax/lsum;
// entropy partials per (b,e,lchunk)
__global__ __launch_bounds__(256) void k5n(
    const __bf16* __restrict__ sc, const float* __restrict__ lmax,
    const float* __restrict__ lsum, __bf16* __restrict__ pb,
    float* __restrict__ entp) {
  int e = blockIdx.x, b = blockIdx.y, lc = blockIdx.z, t = threadIdx.x;
  __shared__ float M_s[8], I_s[8];
  {
    int g = t >> 5, lane = t & 31;
    int eh = e*8 + g;
    const float* lm = lmax + ((size_t)(b*CEH + eh))*128;
    const float* ls = lsum + ((size_t)(b*CEH + eh))*128;
    float M = -1e30f, S = 0.f;
    #pragma unroll
    for (int j = 0; j < 4; j++) {
      float m2 = lm[lane + j*32], s2 = ls[lane + j*32];
      float Mn = fmaxf(M, m2);
      S = S*__expf(M - Mn) + s2*__expf(m2 - Mn);
      M = Mn;
    }
    #pragma unroll
    for (int mask = 16; mask >= 1; mask >>= 1) {
      float Mo = __shfl_xor(M, mask), So = __shfl_xor(S, mask);
      float Mn = fmaxf(M, Mo);
      S = S*__expf(M - Mn) + So*__expf(Mo - Mn);
      M = Mn;
    }
    if (lane == 0) { M_s[g] = M; I_s[g] = 1.f / S; }
  }
  __syncthreads();
  int l = lc*256 + t;
  float pbav = 0.f;
  #pragma unroll
  for (int h = 0; h < 8; h++) {
    size_t ix = ((size_t)(b*CEH + e*8 + h))*CL + l;
    float p = __expf((float)sc[ix] - M_s[h]) * I_s[h];
    pb[ix] = (__bf16)p;
    pbav += p;
  }
  pbav = fmaxf(pbav*0.125f, 1e-12f);
  float ent = -pbav * __logf(pbav);
  __shared__ float red[256];
  red[t] = ent; __syncthreads();
  for (int s = 128; s > 0; s >>= 1) { if (t < s) red[t] += red[t+s]; __syncthreads(); }
  if (t == 0) entp[(b*CE + e)*8 + lc] = red[0];
}

// reff partial[lc][b][eh][d] = sum_{l in 512-chunk} P[b][eh][l] * ret[b][l][d] via bf16 MFMA.
__global__ __launch_bounds__(256) void k6_mfma(
    const __bf16* __restrict__ pb, const float* __restrict__ ret,
    float* __restrict__ part) {
  int b = blockIdx.y;
  int dt = blockIdx.x & 7, lc = blockIdx.x >> 3;
  int d0 = dt*64, l0 = lc*512;
  int t = threadIdx.x, w = t >> 6, lane = t & 63;
  int lnlo = lane & 15, lnhi = lane >> 4;
  __shared__ __bf16 Bs[2][64][40];   // [buf][d][l] transposed ret tile
  f32x4 acc[4];
  #pragma unroll
  for (int et = 0; et < 4; et++) acc[et] = (f32x4){0.f,0.f,0.f,0.f};
  const __bf16* pbb = pb + ((size_t)(b*CEH) + lnlo)*CL + l0 + lnhi*8;
  int srow = t & 31, scol = (t >> 5)*8;
  const float* retb = ret + ((size_t)(b*CL) + l0 + srow)*CD + d0 + scol;
  float4 v0 = *reinterpret_cast<const float4*>(retb);
  float4 v1 = *reinterpret_cast<const float4*>(retb + 4);
  bf16x8 ap0 = *reinterpret_cast<const bf16x8*>(pbb);
  bf16x8 ap1 = *reinterpret_cast<const bf16x8*>(pbb + (size_t)16*CL);
  bf16x8 ap2 = *reinterpret_cast<const bf16x8*>(pbb + (size_t)32*CL);
  bf16x8 ap3 = *reinterpret_cast<const bf16x8*>(pbb + (size_t)48*CL);
  #pragma unroll
  for (int kt = 0; kt < 16; kt++) {
    int cur = kt & 1;
    Bs[cur][scol+0][srow] = (__bf16)v0.x; Bs[cur][scol+1][srow] = (__bf16)v0.y;
    Bs[cur][scol+2][srow] = (__bf16)v0.z; Bs[cur][scol+3][srow] = (__bf16)v0.w;
    Bs[cur][scol+4][srow] = (__bf16)v1.x; Bs[cur][scol+5][srow] = (__bf16)v1.y;
    Bs[cur][scol+6][srow] = (__bf16)v1.z; Bs[cur][scol+7][srow] = (__bf16)v1.w;
    bf16x8 an0, an1, an2, an3;
    if (kt < 15) {
      v0 = *reinterpret_cast<const float4*>(retb + (size_t)(kt+1)*32*CD);
      v1 = *reinterpret_cast<const float4*>(retb + (size_t)(kt+1)*32*CD + 4);
      an0 = *reinterpret_cast<const bf16x8*>(pbb + (kt+1)*32);
      an1 = *reinterpret_cast<const bf16x8*>(pbb + (size_t)16*CL + (kt+1)*32);
      an2 = *reinterpret_cast<const bf16x8*>(pbb + (size_t)32*CL + (kt+1)*32);
      an3 = *reinterpret_cast<const bf16x8*>(pbb + (size_t)48*CL + (kt+1)*32);
    }
    __syncthreads();
    bf16x8 bfrag = *reinterpret_cast<const bf16x8*>(&Bs[cur][w*16 + lnlo][lnhi*8]);
    acc[0] = __builtin_amdgcn_mfma_f32_16x16x32_bf16(ap0, bfrag, acc[0], 0, 0, 0);
    acc[1] = __builtin_amdgcn_mfma_f32_16x16x32_bf16(ap1, bfrag, acc[1], 0, 0, 0);
    acc[2] = __builtin_amdgcn_mfma_f32_16x16x32_bf16(ap2, bfrag, acc[2], 0, 0, 0);
    acc[3] = __builtin_amdgcn_mfma_f32_16x16x32_bf16(ap3, bfrag, acc[3], 0, 0, 0);
    if (kt < 15) { ap0 = an0; ap1 = an1; ap2 = an2; ap3 = an3; }
    __syncthreads();
  }
  float* dst = part + (size_t)lc*(CB*CEH*CD);
  int d = d0 + w*16 + lnlo;
  #pragma unroll
  for (int et = 0; et < 4; et++) {
    #pragma unroll
    for (int i = 0; i < 4; i++) {
      int eh = et*16 + lnhi*4 + i;
      dst[((size_t)(b*CEH + eh))*CD + d] = acc[et][i];
    }
  }
}

extern "C" void kernel_launch(void* const* d_in, const int* in_sizes, int n_in,
                              void* d_out, int out_size, void* d_ws, size_t ws_size,
                              hipStream_t stream) {
  const float* q    = (const float*)d_in[0];
  const float* ret  = (const float*)d_in[1];
  const float* wg   = (const float*)d_in[2];
  const float* lnqg = (const float*)d_in[3];
  const float* lnqb = (const float*)d_in[4];
  const float* Wq   = (const float*)d_in[5];
  const float* bq   = (const float*)d_in[6];
  const float* Wk   = (const float*)d_in[7];
  const float* bk   = (const float*)d_in[8];
  const float* Wv   = (const float*)d_in[9];
  const float* bv   = (const float*)d_in[10];
  const float* Wo   = (const float*)d_in[11];
  const float* bo   = (const float*)d_in[12];
  const float* lnog = (const float*)d_in[13];
  const float* lnob = (const float*)d_in[14];
  const float* W1   = (const float*)d_in[15];
  const float* b1   = (const float*)d_in[16];
  const float* W2   = (const float*)d_in[17];
  const float* b2   = (const float*)d_in[18];

  float* ws = (float*)d_ws;
  float* fused = (float*)d_out;
  float* yout  = fused + CB*CD;
  float* gtout = yout + CB*CE*CD;

  float* sbias = ws + WS_SBIAS;
  __bf16* wkh  = (__bf16*)(ws + WS_WK);
  __bf16* sc   = (__bf16*)(ws + WS_SC);
  float* part0 = ws + WS_PART;
  float* part1 = ws + WS_PART1;
  float* entp  = ws + WS_ENT;
  float* xb    = ws + WS_X;
  float* rpart = ws + WS_RP;
  __bf16* pb16 = (__bf16*)(ws + WS_PB16);
  float* lmax  = rpart;                      // dead before k6_mfma writes rpart
  float* lsum  = rpart + CB*CEH*128;

  // qh partials = LN(q)*g+b @ Wq : LN fused into staging
  gstream_wq<<<dim3(64, CE), 256, 0, stream>>>(q, lnqg, lnqb, Wq, part0);
  // wk_eff (bf16) from Wk and combined qh; dt==0 blocks emit sbias
  k4_wkeff<<<dim3(64, CE), 256, 0, stream>>>(Wk, part0, bq, bk, wkh, sbias);
  k5_mfma<<<dim3(64, CB), 256, 0, stream>>>(ret, wkh, sbias, sc, lmax, lsum);
  k5n<<<dim3(CE, CB, 8), 256, 0, stream>>>(sc, lmax, lsum, pb16, entp);
  k6_mfma<<<dim3(32, CB), 256, 0, stream>>>(pb16, ret, rpart);
  // attn partials (over d-chunks) from reff(=sum 4 rpart) @ Wv
  gstream_v<<<dim3(8, CEH), 256, 0, stream>>>(rpart, Wv, part1);
  // x-partials: (attn = sum part1 + bv) @ Wo
  gstream_wo<<<dim3(64, CE), 256, 0, stream>>>(part1, bv, Wo, part0);
  comb_o<<<CB*CE, 512, 0, stream>>>(part0, bo, q, xb);
  // FFN1 partials = LN(xb)*g+b @ W1 : output-LN fused into staging (coalesced)
  gstream_w1<<<dim3(128, CE), 256, 0, stream>>>(xb, lnog, lnob, W1, part0);
  // y-partials = gelu(FFN1) @ W2 : staging applies bias+GELU (coalesced); -> rpart
  gstream_w2<<<dim3(64, CE), 256, 0, stream>>>(part0, b1, W2, rpart);
  comb_ffn2_final<<<CB, 512, 0, stream>>>(rpart, b2, xb, q, wg, entp, yout, fused, gtout);
}